// Round 11
// baseline (1103.639 us; speedup 1.0000x reference)
//
#include <hip/hip_runtime.h>

constexpr int NUM_USERS = 100000;
constexpr int NUM_ITEMS = 50000;
constexpr int DIM = 64;
constexpr int NNZ_R = 3200000;
constexpr int NNZ_S = 2000000;
constexpr int NNZ_TOT = NNZ_R + NNZ_R + NNZ_S;   // 8.4M entries, one array

constexpr int BSH_U = 8, BROWS_U = 256;     // user/social buckets: 256 rows
constexpr int BSH_I = 7, BROWS_I = 128;     // item buckets: 128 rows
constexpr int NC_U = (NUM_USERS + BROWS_U - 1) / BROWS_U;   // 391
constexpr int NC_I = (NUM_ITEMS + BROWS_I - 1) / BROWS_I;   // 391
constexpr int NC_S = NC_U;                                  // 391
constexpr int NC = NC_U + NC_I + NC_S;                      // 1173
constexpr int NBLK = 512;                   // build blocks (2 per CU)
constexpr int NPB = NBLK * NC;
constexpr int CHUNK_R = NNZ_R / NBLK;       // 6250 exact
constexpr int CHUNK_S = (NNZ_S + NBLK - 1) / NBLK;  // 3907

__device__ __forceinline__ float bf2f(unsigned short u) {
    return __uint_as_float((unsigned)u << 16);
}
__device__ __forceinline__ unsigned short f2bf(float f) {   // round-to-nearest-even
    unsigned u = __float_as_uint(f);
    return (unsigned short)((u + 0x7FFFu + ((u >> 16) & 1u)) >> 16);
}
__device__ __forceinline__ int2 ldnt(const int2* p) {       // nontemporal 8B load
    long long v = __builtin_nontemporal_load(reinterpret_cast<const long long*>(p));
    int2 r;
    r.x = (int)(unsigned)(v & 0xFFFFFFFFll);
    r.y = (int)(unsigned)((unsigned long long)v >> 32);
    return r;
}

// ---- pass A: LDS histogram; per-(block,bucket) counts BUCKET-MAJOR ----
__global__ __launch_bounds__(1024) void hist_lds(const int* __restrict__ rr,
                                                 const int* __restrict__ rc,
                                                 const int* __restrict__ sr,
                                                 int* __restrict__ cntPB /* [NC][NBLK] */) {
    __shared__ int lds[NC];
    int k = blockIdx.x, tid = threadIdx.x;
    for (int c = tid; c < NC; c += 1024) lds[c] = 0;
    __syncthreads();
    int r0 = k * CHUNK_R, r1 = r0 + CHUNK_R;
    int s0 = k * CHUNK_S, s1 = min(s0 + CHUNK_S, NNZ_S);
    for (int i = r0 + tid; i < r1; i += 1024) {
        atomicAdd(&lds[rr[i] >> BSH_U], 1);
        atomicAdd(&lds[NC_U + (rc[i] >> BSH_I)], 1);
    }
    for (int i = s0 + tid; i < s1; i += 1024)
        atomicAdd(&lds[NC_U + NC_I + (sr[i] >> BSH_U)], 1);
    __syncthreads();
    for (int c = tid; c < NC; c += 1024) cntPB[c * NBLK + k] = lds[c];
}

// ---- per-bucket exscan over NBLK block-counts (one block per bucket) ----
__global__ __launch_bounds__(NBLK) void scan_bkt(int* __restrict__ cntPB,
                                                 int* __restrict__ bktTot) {
    int c = blockIdx.x, t = threadIdx.x;
    __shared__ int sh[NBLK];
    int v = cntPB[c * NBLK + t];
    sh[t] = v;
    __syncthreads();
    for (int off = 1; off < NBLK; off <<= 1) {
        int u = (t >= off) ? sh[t - off] : 0;
        __syncthreads();
        sh[t] += u;
        __syncthreads();
    }
    cntPB[c * NBLK + t] = sh[t] - v;
    if (t == NBLK - 1) bktTot[c] = sh[t];
}

// ---- tiny top-level exscan over NC bucket totals ----
__global__ __launch_bounds__(1024) void scan_top(int* __restrict__ B /* NC+1 */) {
    __shared__ int part[1024];
    int t = threadIdx.x;
    const int chunk = (NC + 1023) >> 10;
    int lo = t * chunk, hi = min(lo + chunk, NC);
    int s = 0;
    for (int i = lo; i < hi; ++i) s += B[i];
    part[t] = s;
    __syncthreads();
    for (int off = 1; off < 1024; off <<= 1) {
        int v = (t >= off) ? part[t - off] : 0;
        __syncthreads();
        part[t] += v;
        __syncthreads();
    }
    int excl = (t == 0) ? 0 : part[t - 1];
    for (int i = lo; i < hi; ++i) {
        int v = B[i];
        B[i] = excl;
        excl += v;
    }
    if (t == 1023) B[NC] = part[1023];
}

// ---- pass B: deterministic scatter via exact per-(block,bucket) starts ----
__global__ __launch_bounds__(1024) void bin_pass(const int* __restrict__ rr,
                                                 const int* __restrict__ rc,
                                                 const float* __restrict__ rv,
                                                 const int* __restrict__ sr,
                                                 const int* __restrict__ sc,
                                                 const float* __restrict__ sv,
                                                 const int* __restrict__ cntPB,
                                                 const int* __restrict__ bktBase,
                                                 int2* __restrict__ ent) {
    __shared__ int lds[NC];
    int k = blockIdx.x, tid = threadIdx.x;
    for (int c = tid; c < NC; c += 1024)
        lds[c] = bktBase[c] + cntPB[c * NBLK + k];
    __syncthreads();
    int r0 = k * CHUNK_R, r1 = r0 + CHUNK_R;
    int s0 = k * CHUNK_S, s1 = min(s0 + CHUNK_S, NNZ_S);
    for (int i = r0 + tid; i < r1; i += 1024) {
        int r = rr[i], c = rc[i];
        int v = __float_as_int(rv[i]);
        int pu = atomicAdd(&lds[r >> BSH_U], 1);
        ent[pu] = make_int2(((r & (BROWS_U - 1)) << 17) | c, v);
        int pi = atomicAdd(&lds[NC_U + (c >> BSH_I)], 1);
        ent[pi] = make_int2(((c & (BROWS_I - 1)) << 17) | r, v);
    }
    for (int i = s0 + tid; i < s1; i += 1024) {
        int r = sr[i];
        int ps = atomicAdd(&lds[NC_U + NC_I + (r >> BSH_U)], 1);
        ent[ps] = make_int2(((r & (BROWS_U - 1)) << 17) | sc[i], __float_as_int(sv[i]));
    }
}

// ---- per-bucket counting sort (<=256 local rows) ----
__global__ __launch_bounds__(512) void sort_buckets(const int2* __restrict__ src,
                                                    int2* __restrict__ dst,
                                                    const int* __restrict__ bktBase,
                                                    int* __restrict__ rPu,
                                                    int* __restrict__ rPi,
                                                    int* __restrict__ rPs) {
    int gb = blockIdx.x;
    int* rowptr;
    int brows, lb, nrows;
    if (gb < NC_U)              { rowptr = rPu; brows = BROWS_U; lb = gb;               nrows = NUM_USERS; }
    else if (gb < NC_U + NC_I)  { rowptr = rPi; brows = BROWS_I; lb = gb - NC_U;        nrows = NUM_ITEMS; }
    else                        { rowptr = rPs; brows = BROWS_U; lb = gb - NC_U - NC_I; nrows = NUM_USERS; }
    int t = threadIdx.x;
    __shared__ int cnt[256];
    __shared__ int part[256];
    __shared__ int ofs[256];
    if (t < 256) cnt[t] = 0;
    __syncthreads();
    int b0 = bktBase[gb], b1 = bktBase[gb + 1];
    for (int i = b0 + t; i < b1; i += 512)
        atomicAdd(&cnt[(unsigned)src[i].x >> 17], 1);
    __syncthreads();
    if (t < 256) part[t] = cnt[t];
    __syncthreads();
    for (int off = 1; off < 256; off <<= 1) {
        int v = 0;
        if (t < 256 && t >= off) v = part[t - off];
        __syncthreads();
        if (t < 256) part[t] += v;
        __syncthreads();
    }
    if (t < 256) ofs[t] = part[t] - cnt[t];
    __syncthreads();
    int gr = lb * brows + t;
    if (t < brows && gr < nrows) rowptr[gr] = b0 + ofs[t];
    if (gb == 0 && t == 0) {
        rPu[NUM_USERS] = NNZ_R;
        rPi[NUM_ITEMS] = 2 * NNZ_R;
        rPs[NUM_USERS] = NNZ_TOT;
    }
    __syncthreads();
    for (int i = b0 + t; i < b1; i += 512) {
        int2 v = src[i];
        int lr = (unsigned)v.x >> 17;
        int pos = b0 + atomicAdd(&ofs[lr], 1);
        dst[pos] = make_int2(v.x & 0x1FFFF, v.y);
    }
}

// ---- CSR SpMM, 3 independent ops per dispatch; NT entry loads; bf16 gathers;
//      f32 register accumulation; optional acc RMW / optional bf16 out ----
struct SpmmOp {
    const int* rowptr;
    const int2* ent;
    const unsigned short* x;    // bf16 rows [*][64]
    unsigned short* out;        // bf16, nullable
    float* acc;                 // f32, nullable
    float w;
    int nrows;
};

__global__ __launch_bounds__(256, 4) void spmm3(SpmmOp A, SpmmOp B, SpmmOp C,
                                                int na, int nab) {
    int b = blockIdx.x;
    SpmmOp op;
    if (b < na)       { op = A; }
    else if (b < nab) { op = B; b -= na; }
    else              { op = C; b -= nab; }
    int row = b * 4 + (threadIdx.x >> 6);
    if (row >= op.nrows) return;
    int d = threadIdx.x & 63;
    const int2* __restrict__ ent = op.ent;
    const unsigned short* __restrict__ x = op.x;
    int e = op.rowptr[row], end = op.rowptr[row + 1];
    float s0 = 0.f, s1 = 0.f, s2 = 0.f, s3 = 0.f, s4 = 0.f, s5 = 0.f, s6 = 0.f, s7 = 0.f;
    for (; e + 8 <= end; e += 8) {
        int2 e0 = ldnt(ent + e),     e1 = ldnt(ent + e + 1);
        int2 e2 = ldnt(ent + e + 2), e3 = ldnt(ent + e + 3);
        int2 e4 = ldnt(ent + e + 4), e5 = ldnt(ent + e + 5);
        int2 e6 = ldnt(ent + e + 6), e7 = ldnt(ent + e + 7);
        float x0 = bf2f(x[(size_t)e0.x * DIM + d]);
        float x1 = bf2f(x[(size_t)e1.x * DIM + d]);
        float x2 = bf2f(x[(size_t)e2.x * DIM + d]);
        float x3 = bf2f(x[(size_t)e3.x * DIM + d]);
        float x4 = bf2f(x[(size_t)e4.x * DIM + d]);
        float x5 = bf2f(x[(size_t)e5.x * DIM + d]);
        float x6 = bf2f(x[(size_t)e6.x * DIM + d]);
        float x7 = bf2f(x[(size_t)e7.x * DIM + d]);
        s0 += __int_as_float(e0.y) * x0;
        s1 += __int_as_float(e1.y) * x1;
        s2 += __int_as_float(e2.y) * x2;
        s3 += __int_as_float(e3.y) * x3;
        s4 += __int_as_float(e4.y) * x4;
        s5 += __int_as_float(e5.y) * x5;
        s6 += __int_as_float(e6.y) * x6;
        s7 += __int_as_float(e7.y) * x7;
    }
    for (; e < end; ++e) {
        int2 t = ldnt(ent + e);
        s0 += __int_as_float(t.y) * bf2f(x[(size_t)t.x * DIM + d]);
    }
    float sum = ((s0 + s1) + (s2 + s3)) + ((s4 + s5) + (s6 + s7));
    size_t idx = (size_t)row * DIM + d;
    if (op.out) __builtin_nontemporal_store(f2bf(sum), &op.out[idx]);
    if (op.acc) op.acc[idx] += op.w * sum;
}

// acc init + bf16 copies of inputs (after build; aliases build entries)
__global__ void init_acc(const float* __restrict__ ue, const float* __restrict__ ie,
                         float* __restrict__ accU, float* __restrict__ accI,
                         unsigned short* __restrict__ ueB, unsigned short* __restrict__ ieB,
                         int u4, int i4) {
    const float wu = 0.6f / 4.0f + 0.4f / 3.0f;
    const float wi = 0.25f;
    int i = blockIdx.x * blockDim.x + threadIdx.x;
    int st = gridDim.x * blockDim.x;
    int n4 = u4 + i4;
    for (; i < n4; i += st) {
        if (i < u4) {
            float4 v = reinterpret_cast<const float4*>(ue)[i];
            reinterpret_cast<float4*>(accU)[i] = make_float4(wu * v.x, wu * v.y, wu * v.z, wu * v.w);
            ushort4 b;
            b.x = f2bf(v.x); b.y = f2bf(v.y); b.z = f2bf(v.z); b.w = f2bf(v.w);
            reinterpret_cast<ushort4*>(ueB)[i] = b;
        } else {
            int j = i - u4;
            float4 v = reinterpret_cast<const float4*>(ie)[j];
            reinterpret_cast<float4*>(accI)[j] = make_float4(wi * v.x, wi * v.y, wi * v.z, wi * v.w);
            ushort4 b;
            b.x = f2bf(v.x); b.y = f2bf(v.y); b.z = f2bf(v.z); b.w = f2bf(v.w);
            reinterpret_cast<ushort4*>(ieB)[j] = b;
        }
    }
}

// final: users add WS*(s1+s2) then L2-normalize; items just normalize
__global__ void finalize_kernel(float* __restrict__ out,
                                const unsigned short* __restrict__ s1,
                                const unsigned short* __restrict__ s2) {
    const float WS = 0.4f / 3.0f;
    int row = blockIdx.x * 4 + (threadIdx.x >> 6);
    if (row >= NUM_USERS + NUM_ITEMS) return;
    int d = threadIdx.x & 63;
    int idx = row * DIM + d;
    float val = out[idx];
    if (row < NUM_USERS) val += WS * (bf2f(s1[idx]) + bf2f(s2[idx]));
    float sq = val * val;
    #pragma unroll
    for (int off = 32; off; off >>= 1) sq += __shfl_xor(sq, off, 64);
    out[idx] = val / fmaxf(sqrtf(sq), 1e-12f);
}

extern "C" void kernel_launch(void* const* d_in, const int* in_sizes, int n_in,
                              void* d_out, int out_size, void* d_ws, size_t ws_size,
                              hipStream_t stream) {
    const float* user_emb = (const float*)d_in[0];
    const float* item_emb = (const float*)d_in[1];
    const float* r_vals   = (const float*)d_in[2];
    const float* s_vals   = (const float*)d_in[3];
    const int*   r_rows   = (const int*)d_in[4];
    const int*   r_cols   = (const int*)d_in[5];
    const int*   s_rows   = (const int*)d_in[6];
    const int*   s_cols   = (const int*)d_in[7];

    const size_t U = (size_t)NUM_USERS * DIM;
    const size_t I = (size_t)NUM_ITEMS * DIM;

    // ---- workspace (~141 MB) ----
    int2* ent_sorted = (int2*)d_ws;                       // NNZ_TOT (67.2 MB), persistent
    char* region2 = (char*)(ent_sorted + NNZ_TOT);        // 70.4 MB union:
    int2* ent_bin = (int2*)region2;                       //   build-time entries (67.2)
    unsigned short* ueB = (unsigned short*)region2;       //   spmm-time bf16 dense:
    unsigned short* ieB = ueB + U;                        //   [ueB 12.8][ieB 6.4][uA 12.8]
    unsigned short* uA  = ieB + I;                        //   [uB 12.8][iA 6.4][iB 6.4]
    unsigned short* uB  = uA + U;                         //   [s1 12.8]
    unsigned short* iA  = uB + U;
    unsigned short* iB  = iA + I;
    unsigned short* s1b = iB + I;
    unsigned short* s2b = ueB;                            // aliases ueB (dead after D1)
    int* cntPB   = (int*)(region2 + (size_t)NNZ_TOT * 8 + U * 2);  // past ent_bin & s1b
    int* bktBase = cntPB + NPB;
    int* rPu = bktBase + NC + 1;
    int* rPi = rPu + NUM_USERS + 1;
    int* rPs = rPi + NUM_ITEMS + 1;

    float* accU = (float*)d_out;
    float* accI = (float*)d_out + U;

    dim3 blk(256);

    // ---- build: hist -> scans -> deterministic scatter -> per-bucket sort ----
    hist_lds<<<NBLK, 1024, 0, stream>>>(r_rows, r_cols, s_rows, cntPB);
    scan_bkt<<<NC, NBLK, 0, stream>>>(cntPB, bktBase);
    scan_top<<<1, 1024, 0, stream>>>(bktBase);
    bin_pass<<<NBLK, 1024, 0, stream>>>(r_rows, r_cols, r_vals, s_rows, s_cols, s_vals,
                                        cntPB, bktBase, ent_bin);
    sort_buckets<<<NC, 512, 0, stream>>>(ent_bin, ent_sorted, bktBase, rPu, rPi, rPs);

    init_acc<<<2048, blk, 0, stream>>>(user_emb, item_emb, accU, accI, ueB, ieB,
                                       (int)(U / 4), (int)(I / 4));

    // ---- propagation: 3 fused dispatches (bipartite x2 + social per dispatch) ----
    const float WU = 0.6f / 4.0f, WI = 0.25f;
    int ub = (NUM_USERS + 3) / 4, ib = (NUM_ITEMS + 3) / 4;

    // D1: u1 = R@ieB (acc), i1 = R^T@ueB (acc), s1 = S@ueB (out only)
    SpmmOp u1{rPu, ent_sorted, ieB, uA, accU, WU, NUM_USERS};
    SpmmOp i1{rPi, ent_sorted, ueB, iA, accI, WI, NUM_ITEMS};
    SpmmOp so1{rPs, ent_sorted, ueB, s1b, nullptr, 0.f, NUM_USERS};
    spmm3<<<ub + ib + ub, blk, 0, stream>>>(u1, i1, so1, ub, ub + ib);

    // D2: u2 = R@iA (acc), i2 = R^T@uA (acc), s2 = S@s1 (out only, into dead ueB)
    SpmmOp u2{rPu, ent_sorted, iA, uB, accU, WU, NUM_USERS};
    SpmmOp i2{rPi, ent_sorted, uA, iB, accI, WI, NUM_ITEMS};
    SpmmOp so2{rPs, ent_sorted, s1b, s2b, nullptr, 0.f, NUM_USERS};
    spmm3<<<ub + ib + ub, blk, 0, stream>>>(u2, i2, so2, ub, ub + ib);

    // D3: u3, i3 acc-only
    SpmmOp u3{rPu, ent_sorted, iB, nullptr, accU, WU, NUM_USERS};
    SpmmOp i3{rPi, ent_sorted, uB, nullptr, accI, WI, NUM_ITEMS};
    spmm3<<<ub + ib, blk, 0, stream>>>(u3, i3, i3, ub, ub + ib);

    finalize_kernel<<<(NUM_USERS + NUM_ITEMS + 3) / 4, blk, 0, stream>>>(
        (float*)d_out, s1b, s2b);
}

// Round 12
// 736.339 us; speedup vs baseline: 1.4988x; 1.4988x over previous
//
#include <hip/hip_runtime.h>

constexpr int NUM_USERS = 100000;
constexpr int NUM_ITEMS = 50000;
constexpr int DIM = 64;
constexpr int NNZ_R = 3200000;
constexpr int NNZ_S = 2000000;
constexpr int NNZ_TOT = NNZ_R + NNZ_R + NNZ_S;   // 8.4M entries, one array

constexpr int BSH_U = 8, BROWS_U = 256;     // user/social buckets: 256 rows
constexpr int BSH_I = 7, BROWS_I = 128;     // item buckets: 128 rows
constexpr int NC_U = (NUM_USERS + BROWS_U - 1) / BROWS_U;   // 391
constexpr int NC_I = (NUM_ITEMS + BROWS_I - 1) / BROWS_I;   // 391
constexpr int NC_S = NC_U;                                  // 391
constexpr int NC = NC_U + NC_I + NC_S;                      // 1173
constexpr int NBLK = 512;                   // build blocks (2 per CU)
constexpr int NPB = NBLK * NC;
constexpr int CHUNK_R = NNZ_R / NBLK;       // 6250 exact
constexpr int CHUNK_S = (NNZ_S + NBLK - 1) / NBLK;  // 3907

__device__ __forceinline__ float bf2f(unsigned short u) {
    return __uint_as_float((unsigned)u << 16);
}
__device__ __forceinline__ unsigned short f2bf(float f) {   // round-to-nearest-even
    unsigned u = __float_as_uint(f);
    return (unsigned short)((u + 0x7FFFu + ((u >> 16) & 1u)) >> 16);
}
__device__ __forceinline__ float bflo(unsigned r) { return __uint_as_float(r << 16); }
__device__ __forceinline__ float bfhi(unsigned r) { return __uint_as_float(r & 0xFFFF0000u); }

// ---- pass A: LDS histogram; per-(block,bucket) counts BUCKET-MAJOR ----
__global__ __launch_bounds__(1024) void hist_lds(const int* __restrict__ rr,
                                                 const int* __restrict__ rc,
                                                 const int* __restrict__ sr,
                                                 int* __restrict__ cntPB /* [NC][NBLK] */) {
    __shared__ int lds[NC];
    int k = blockIdx.x, tid = threadIdx.x;
    for (int c = tid; c < NC; c += 1024) lds[c] = 0;
    __syncthreads();
    int r0 = k * CHUNK_R, r1 = r0 + CHUNK_R;
    int s0 = k * CHUNK_S, s1 = min(s0 + CHUNK_S, NNZ_S);
    for (int i = r0 + tid; i < r1; i += 1024) {
        atomicAdd(&lds[rr[i] >> BSH_U], 1);
        atomicAdd(&lds[NC_U + (rc[i] >> BSH_I)], 1);
    }
    for (int i = s0 + tid; i < s1; i += 1024)
        atomicAdd(&lds[NC_U + NC_I + (sr[i] >> BSH_U)], 1);
    __syncthreads();
    for (int c = tid; c < NC; c += 1024) cntPB[c * NBLK + k] = lds[c];
}

// ---- per-bucket exscan over NBLK block-counts (one block per bucket) ----
__global__ __launch_bounds__(NBLK) void scan_bkt(int* __restrict__ cntPB,
                                                 int* __restrict__ bktTot) {
    int c = blockIdx.x, t = threadIdx.x;
    __shared__ int sh[NBLK];
    int v = cntPB[c * NBLK + t];
    sh[t] = v;
    __syncthreads();
    for (int off = 1; off < NBLK; off <<= 1) {
        int u = (t >= off) ? sh[t - off] : 0;
        __syncthreads();
        sh[t] += u;
        __syncthreads();
    }
    cntPB[c * NBLK + t] = sh[t] - v;
    if (t == NBLK - 1) bktTot[c] = sh[t];
}

// ---- tiny top-level exscan over NC bucket totals ----
__global__ __launch_bounds__(1024) void scan_top(int* __restrict__ B /* NC+1 */) {
    __shared__ int part[1024];
    int t = threadIdx.x;
    const int chunk = (NC + 1023) >> 10;
    int lo = t * chunk, hi = min(lo + chunk, NC);
    int s = 0;
    for (int i = lo; i < hi; ++i) s += B[i];
    part[t] = s;
    __syncthreads();
    for (int off = 1; off < 1024; off <<= 1) {
        int v = (t >= off) ? part[t - off] : 0;
        __syncthreads();
        part[t] += v;
        __syncthreads();
    }
    int excl = (t == 0) ? 0 : part[t - 1];
    for (int i = lo; i < hi; ++i) {
        int v = B[i];
        B[i] = excl;
        excl += v;
    }
    if (t == 1023) B[NC] = part[1023];
}

// ---- pass B: deterministic scatter via exact per-(block,bucket) starts ----
__global__ __launch_bounds__(1024) void bin_pass(const int* __restrict__ rr,
                                                 const int* __restrict__ rc,
                                                 const float* __restrict__ rv,
                                                 const int* __restrict__ sr,
                                                 const int* __restrict__ sc,
                                                 const float* __restrict__ sv,
                                                 const int* __restrict__ cntPB,
                                                 const int* __restrict__ bktBase,
                                                 int2* __restrict__ ent) {
    __shared__ int lds[NC];
    int k = blockIdx.x, tid = threadIdx.x;
    for (int c = tid; c < NC; c += 1024)
        lds[c] = bktBase[c] + cntPB[c * NBLK + k];
    __syncthreads();
    int r0 = k * CHUNK_R, r1 = r0 + CHUNK_R;
    int s0 = k * CHUNK_S, s1 = min(s0 + CHUNK_S, NNZ_S);
    for (int i = r0 + tid; i < r1; i += 1024) {
        int r = rr[i], c = rc[i];
        int v = __float_as_int(rv[i]);
        int pu = atomicAdd(&lds[r >> BSH_U], 1);
        ent[pu] = make_int2(((r & (BROWS_U - 1)) << 17) | c, v);
        int pi = atomicAdd(&lds[NC_U + (c >> BSH_I)], 1);
        ent[pi] = make_int2(((c & (BROWS_I - 1)) << 17) | r, v);
    }
    for (int i = s0 + tid; i < s1; i += 1024) {
        int r = sr[i];
        int ps = atomicAdd(&lds[NC_U + NC_I + (r >> BSH_U)], 1);
        ent[ps] = make_int2(((r & (BROWS_U - 1)) << 17) | sc[i], __float_as_int(sv[i]));
    }
}

// ---- per-bucket counting sort (<=256 local rows) ----
__global__ __launch_bounds__(512) void sort_buckets(const int2* __restrict__ src,
                                                    int2* __restrict__ dst,
                                                    const int* __restrict__ bktBase,
                                                    int* __restrict__ rPu,
                                                    int* __restrict__ rPi,
                                                    int* __restrict__ rPs) {
    int gb = blockIdx.x;
    int* rowptr;
    int brows, lb, nrows;
    if (gb < NC_U)              { rowptr = rPu; brows = BROWS_U; lb = gb;               nrows = NUM_USERS; }
    else if (gb < NC_U + NC_I)  { rowptr = rPi; brows = BROWS_I; lb = gb - NC_U;        nrows = NUM_ITEMS; }
    else                        { rowptr = rPs; brows = BROWS_U; lb = gb - NC_U - NC_I; nrows = NUM_USERS; }
    int t = threadIdx.x;
    __shared__ int cnt[256];
    __shared__ int part[256];
    __shared__ int ofs[256];
    if (t < 256) cnt[t] = 0;
    __syncthreads();
    int b0 = bktBase[gb], b1 = bktBase[gb + 1];
    for (int i = b0 + t; i < b1; i += 512)
        atomicAdd(&cnt[(unsigned)src[i].x >> 17], 1);
    __syncthreads();
    if (t < 256) part[t] = cnt[t];
    __syncthreads();
    for (int off = 1; off < 256; off <<= 1) {
        int v = 0;
        if (t < 256 && t >= off) v = part[t - off];
        __syncthreads();
        if (t < 256) part[t] += v;
        __syncthreads();
    }
    if (t < 256) ofs[t] = part[t] - cnt[t];
    __syncthreads();
    int gr = lb * brows + t;
    if (t < brows && gr < nrows) rowptr[gr] = b0 + ofs[t];
    if (gb == 0 && t == 0) {
        rPu[NUM_USERS] = NNZ_R;
        rPi[NUM_ITEMS] = 2 * NNZ_R;
        rPs[NUM_USERS] = NNZ_TOT;
    }
    __syncthreads();
    for (int i = b0 + t; i < b1; i += 512) {
        int2 v = src[i];
        int lr = (unsigned)v.x >> 17;
        int pos = b0 + atomicAdd(&ofs[lr], 1);
        dst[pos] = make_int2(v.x & 0x1FFFF, v.y);
    }
}

// ---- CSR SpMM: one row per wave, 16 lanes per row-quarter (uint2 = 4 bf16 dims),
//      4 edges per gather instruction, 16 edges in flight; f32 accumulate;
//      butterfly cross-group reduce; fused weighted acc. Two ops per dispatch. ----
struct SpmmOp {
    const int* rowptr;
    const int2* ent;
    const unsigned short* x;    // bf16 rows [*][64]
    unsigned short* out;        // bf16, nullable
    float* acc;                 // f32 (d_out), always valid
    float w;
    int nrows;
};

__global__ __launch_bounds__(256, 4) void spmm2(SpmmOp A, SpmmOp B, int ablocks) {
    bool isA = (int)blockIdx.x < ablocks;
    SpmmOp op = isA ? A : B;
    int bid = isA ? blockIdx.x : blockIdx.x - ablocks;
    int row = bid * 4 + (threadIdx.x >> 6);
    if (row >= op.nrows) return;
    int lane = threadIdx.x & 63;
    int g = lane >> 4;          // edge group 0..3
    int q = lane & 15;          // quarter-row slot: dims 4q..4q+3
    const int2* __restrict__ ent = op.ent;
    const unsigned short* __restrict__ x = op.x;
    int e = op.rowptr[row], end = op.rowptr[row + 1];
    float s0 = 0.f, s1 = 0.f, s2 = 0.f, s3 = 0.f;
    for (; e + 16 <= end; e += 16) {            // 4 edges per group, 16 per wave-iter
        int2 n0 = ent[e + g];
        int2 n1 = ent[e + 4 + g];
        int2 n2 = ent[e + 8 + g];
        int2 n3 = ent[e + 12 + g];
        uint2 r0 = *reinterpret_cast<const uint2*>(x + (size_t)n0.x * DIM + q * 4);
        uint2 r1 = *reinterpret_cast<const uint2*>(x + (size_t)n1.x * DIM + q * 4);
        uint2 r2 = *reinterpret_cast<const uint2*>(x + (size_t)n2.x * DIM + q * 4);
        uint2 r3 = *reinterpret_cast<const uint2*>(x + (size_t)n3.x * DIM + q * 4);
        float v0 = __int_as_float(n0.y), v1 = __int_as_float(n1.y);
        float v2 = __int_as_float(n2.y), v3 = __int_as_float(n3.y);
        s0 += v0 * bflo(r0.x); s1 += v0 * bfhi(r0.x); s2 += v0 * bflo(r0.y); s3 += v0 * bfhi(r0.y);
        s0 += v1 * bflo(r1.x); s1 += v1 * bfhi(r1.x); s2 += v1 * bflo(r1.y); s3 += v1 * bfhi(r1.y);
        s0 += v2 * bflo(r2.x); s1 += v2 * bfhi(r2.x); s2 += v2 * bflo(r2.y); s3 += v2 * bfhi(r2.y);
        s0 += v3 * bflo(r3.x); s1 += v3 * bfhi(r3.x); s2 += v3 * bflo(r3.y); s3 += v3 * bfhi(r3.y);
    }
    for (; e < end; e += 4) {                   // tail: up to 4 edges per step
        if (e + g < end) {
            int2 n = ent[e + g];
            uint2 r = *reinterpret_cast<const uint2*>(x + (size_t)n.x * DIM + q * 4);
            float v = __int_as_float(n.y);
            s0 += v * bflo(r.x); s1 += v * bfhi(r.x);
            s2 += v * bflo(r.y); s3 += v * bfhi(r.y);
        }
    }
    // combine the 4 edge-groups (butterfly over lane bits 4,5)
    s0 += __shfl_xor(s0, 16, 64); s0 += __shfl_xor(s0, 32, 64);
    s1 += __shfl_xor(s1, 16, 64); s1 += __shfl_xor(s1, 32, 64);
    s2 += __shfl_xor(s2, 16, 64); s2 += __shfl_xor(s2, 32, 64);
    s3 += __shfl_xor(s3, 16, 64); s3 += __shfl_xor(s3, 32, 64);
    if (g == 0) {                               // 16 lanes write the full row
        size_t base = (size_t)row * DIM + q * 4;
        if (op.out) {
            uint2 o;
            o.x = (unsigned)f2bf(s0) | ((unsigned)f2bf(s1) << 16);
            o.y = (unsigned)f2bf(s2) | ((unsigned)f2bf(s3) << 16);
            *reinterpret_cast<uint2*>(op.out + base) = o;
        }
        float4* a = reinterpret_cast<float4*>(op.acc + base);
        float4 av = *a;
        av.x += op.w * s0; av.y += op.w * s1; av.z += op.w * s2; av.w += op.w * s3;
        *a = av;
    }
}

// acc init + bf16 copies of inputs (after build; aliases build entries)
__global__ void init_acc(const float* __restrict__ ue, const float* __restrict__ ie,
                         float* __restrict__ accU, float* __restrict__ accI,
                         unsigned short* __restrict__ ueB, unsigned short* __restrict__ ieB,
                         int u4, int i4) {
    const float wu = 0.6f / 4.0f + 0.4f / 3.0f;
    const float wi = 0.25f;
    int i = blockIdx.x * blockDim.x + threadIdx.x;
    int st = gridDim.x * blockDim.x;
    int n4 = u4 + i4;
    for (; i < n4; i += st) {
        if (i < u4) {
            float4 v = reinterpret_cast<const float4*>(ue)[i];
            reinterpret_cast<float4*>(accU)[i] = make_float4(wu * v.x, wu * v.y, wu * v.z, wu * v.w);
            ushort4 b;
            b.x = f2bf(v.x); b.y = f2bf(v.y); b.z = f2bf(v.z); b.w = f2bf(v.w);
            reinterpret_cast<ushort4*>(ueB)[i] = b;
        } else {
            int j = i - u4;
            float4 v = reinterpret_cast<const float4*>(ie)[j];
            reinterpret_cast<float4*>(accI)[j] = make_float4(wi * v.x, wi * v.y, wi * v.z, wi * v.w);
            ushort4 b;
            b.x = f2bf(v.x); b.y = f2bf(v.y); b.z = f2bf(v.z); b.w = f2bf(v.w);
            reinterpret_cast<ushort4*>(ieB)[j] = b;
        }
    }
}

__global__ void finalize_kernel(float* __restrict__ out, int nrows) {
    int row = blockIdx.x * 4 + (threadIdx.x >> 6);
    if (row >= nrows) return;
    int d = threadIdx.x & 63;
    int idx = row * DIM + d;
    float val = out[idx];
    float sq = val * val;
    #pragma unroll
    for (int off = 32; off; off >>= 1) sq += __shfl_xor(sq, off, 64);
    out[idx] = val / fmaxf(sqrtf(sq), 1e-12f);
}

extern "C" void kernel_launch(void* const* d_in, const int* in_sizes, int n_in,
                              void* d_out, int out_size, void* d_ws, size_t ws_size,
                              hipStream_t stream) {
    const float* user_emb = (const float*)d_in[0];
    const float* item_emb = (const float*)d_in[1];
    const float* r_vals   = (const float*)d_in[2];
    const float* s_vals   = (const float*)d_in[3];
    const int*   r_rows   = (const int*)d_in[4];
    const int*   r_cols   = (const int*)d_in[5];
    const int*   s_rows   = (const int*)d_in[6];
    const int*   s_cols   = (const int*)d_in[7];

    const size_t U = (size_t)NUM_USERS * DIM;
    const size_t I = (size_t)NUM_ITEMS * DIM;

    // ---- workspace (~138 MB, round-10 layout) ----
    int2* ent_sorted = (int2*)d_ws;                       // NNZ_TOT (67.2 MB), persistent
    char* region2 = (char*)(ent_sorted + NNZ_TOT);        // 67.2 MB union:
    int2* ent_bin = (int2*)region2;                       //   build-time entries
    unsigned short* ueB = (unsigned short*)region2;       //   spmm-time bf16 dense (57.6 MB)
    unsigned short* ieB = ueB + U;
    unsigned short* uA  = ieB + I;
    unsigned short* uB  = uA + U;
    unsigned short* iA  = uB + U;
    unsigned short* iB  = iA + I;
    int* cntPB   = (int*)(region2 + (size_t)NNZ_TOT * 8); // [NC][NBLK] (2.4 MB)
    int* bktBase = cntPB + NPB;                           // NC+1
    int* rPu = bktBase + NC + 1;                          // NUM_USERS+1
    int* rPi = rPu + NUM_USERS + 1;                       // NUM_ITEMS+1
    int* rPs = rPi + NUM_ITEMS + 1;                       // NUM_USERS+1

    float* accU = (float*)d_out;
    float* accI = (float*)d_out + U;

    dim3 blk(256);

    // ---- build: hist -> per-bucket scan -> top scan -> deterministic scatter -> sort ----
    hist_lds<<<NBLK, 1024, 0, stream>>>(r_rows, r_cols, s_rows, cntPB);
    scan_bkt<<<NC, NBLK, 0, stream>>>(cntPB, bktBase);
    scan_top<<<1, 1024, 0, stream>>>(bktBase);
    bin_pass<<<NBLK, 1024, 0, stream>>>(r_rows, r_cols, r_vals, s_rows, s_cols, s_vals,
                                        cntPB, bktBase, ent_bin);
    sort_buckets<<<NC, 512, 0, stream>>>(ent_bin, ent_sorted, bktBase, rPu, rPi, rPs);

    init_acc<<<2048, blk, 0, stream>>>(user_emb, item_emb, accU, accI, ueB, ieB,
                                       (int)(U / 4), (int)(I / 4));

    // ---- 3 bipartite layers, both directions fused per dispatch ----
    const float WU = 0.6f / 4.0f, WI = 0.25f, WS = 0.4f / 3.0f;
    int ub = (NUM_USERS + 3) / 4, ib = (NUM_ITEMS + 3) / 4;

    SpmmOp u1{rPu, ent_sorted, ieB, uA, accU, WU, NUM_USERS};
    SpmmOp i1{rPi, ent_sorted, ueB, iA, accI, WI, NUM_ITEMS};
    spmm2<<<ub + ib, blk, 0, stream>>>(u1, i1, ub);

    SpmmOp u2{rPu, ent_sorted, iA, uB, accU, WU, NUM_USERS};
    SpmmOp i2{rPi, ent_sorted, uA, iB, accI, WI, NUM_ITEMS};
    spmm2<<<ub + ib, blk, 0, stream>>>(u2, i2, ub);

    SpmmOp u3{rPu, ent_sorted, iB, nullptr, accU, WU, NUM_USERS};
    SpmmOp i3{rPi, ent_sorted, uB, nullptr, accI, WI, NUM_ITEMS};
    spmm2<<<ub + ib, blk, 0, stream>>>(u3, i3, ub);

    // ---- 2 social layers (uA dead after layer 2 -> reuse as social ping) ----
    SpmmOp so1{rPs, ent_sorted, ueB, uA, accU, WS, NUM_USERS};
    spmm2<<<ub, blk, 0, stream>>>(so1, so1, ub);
    SpmmOp so2{rPs, ent_sorted, uA, nullptr, accU, WS, NUM_USERS};
    spmm2<<<ub, blk, 0, stream>>>(so2, so2, ub);

    finalize_kernel<<<(NUM_USERS + NUM_ITEMS + 3) / 4, blk, 0, stream>>>(
        (float*)d_out, NUM_USERS + NUM_ITEMS);
}

// Round 13
// 705.500 us; speedup vs baseline: 1.5643x; 1.0437x over previous
//
#include <hip/hip_runtime.h>

constexpr int NUM_USERS = 100000;
constexpr int NUM_ITEMS = 50000;
constexpr int DIM = 64;
constexpr int NNZ_R = 3200000;
constexpr int NNZ_S = 2000000;
constexpr int NNZ_TOT = NNZ_R + NNZ_R + NNZ_S;   // 8.4M entries, one array

constexpr int BSH_U = 8, BROWS_U = 256;     // user/social buckets: 256 rows
constexpr int BSH_I = 7, BROWS_I = 128;     // item buckets: 128 rows
constexpr int NC_U = (NUM_USERS + BROWS_U - 1) / BROWS_U;   // 391
constexpr int NC_I = (NUM_ITEMS + BROWS_I - 1) / BROWS_I;   // 391
constexpr int NC_S = NC_U;                                  // 391
constexpr int NC = NC_U + NC_I + NC_S;                      // 1173
constexpr int NBLK = 256;                   // build blocks: 1/CU -> dirty-line set 2.4MB/XCD < 4MB L2
constexpr int NPB = NBLK * NC;
constexpr int CHUNK_R = NNZ_R / NBLK;       // 12500 exact
constexpr int CHUNK_S = (NNZ_S + NBLK - 1) / NBLK;  // 7813

__device__ __forceinline__ float bf2f(unsigned short u) {
    return __uint_as_float((unsigned)u << 16);
}
__device__ __forceinline__ unsigned short f2bf(float f) {   // round-to-nearest-even
    unsigned u = __float_as_uint(f);
    return (unsigned short)((u + 0x7FFFu + ((u >> 16) & 1u)) >> 16);
}
__device__ __forceinline__ float bflo(unsigned r) { return __uint_as_float(r << 16); }
__device__ __forceinline__ float bfhi(unsigned r) { return __uint_as_float(r & 0xFFFF0000u); }

// ---- pass A: LDS histogram; per-(block,bucket) counts BUCKET-MAJOR ----
__global__ __launch_bounds__(1024) void hist_lds(const int* __restrict__ rr,
                                                 const int* __restrict__ rc,
                                                 const int* __restrict__ sr,
                                                 int* __restrict__ cntPB /* [NC][NBLK] */) {
    __shared__ int lds[NC];
    int k = blockIdx.x, tid = threadIdx.x;
    for (int c = tid; c < NC; c += 1024) lds[c] = 0;
    __syncthreads();
    int r0 = k * CHUNK_R, r1 = r0 + CHUNK_R;
    int s0 = k * CHUNK_S, s1 = min(s0 + CHUNK_S, NNZ_S);
    for (int i = r0 + tid; i < r1; i += 1024) {
        atomicAdd(&lds[rr[i] >> BSH_U], 1);
        atomicAdd(&lds[NC_U + (rc[i] >> BSH_I)], 1);
    }
    for (int i = s0 + tid; i < s1; i += 1024)
        atomicAdd(&lds[NC_U + NC_I + (sr[i] >> BSH_U)], 1);
    __syncthreads();
    for (int c = tid; c < NC; c += 1024) cntPB[c * NBLK + k] = lds[c];
}

// ---- per-bucket exscan over NBLK block-counts (one block per bucket) ----
__global__ __launch_bounds__(NBLK) void scan_bkt(int* __restrict__ cntPB,
                                                 int* __restrict__ bktTot) {
    int c = blockIdx.x, t = threadIdx.x;
    __shared__ int sh[NBLK];
    int v = cntPB[c * NBLK + t];
    sh[t] = v;
    __syncthreads();
    for (int off = 1; off < NBLK; off <<= 1) {
        int u = (t >= off) ? sh[t - off] : 0;
        __syncthreads();
        sh[t] += u;
        __syncthreads();
    }
    cntPB[c * NBLK + t] = sh[t] - v;
    if (t == NBLK - 1) bktTot[c] = sh[t];
}

// ---- tiny top-level exscan over NC bucket totals ----
__global__ __launch_bounds__(1024) void scan_top(int* __restrict__ B /* NC+1 */) {
    __shared__ int part[1024];
    int t = threadIdx.x;
    const int chunk = (NC + 1023) >> 10;
    int lo = t * chunk, hi = min(lo + chunk, NC);
    int s = 0;
    for (int i = lo; i < hi; ++i) s += B[i];
    part[t] = s;
    __syncthreads();
    for (int off = 1; off < 1024; off <<= 1) {
        int v = (t >= off) ? part[t - off] : 0;
        __syncthreads();
        part[t] += v;
        __syncthreads();
    }
    int excl = (t == 0) ? 0 : part[t - 1];
    for (int i = lo; i < hi; ++i) {
        int v = B[i];
        B[i] = excl;
        excl += v;
    }
    if (t == 1023) B[NC] = part[1023];
}

// ---- pass B: deterministic scatter via exact per-(block,bucket) starts ----
__global__ __launch_bounds__(1024) void bin_pass(const int* __restrict__ rr,
                                                 const int* __restrict__ rc,
                                                 const float* __restrict__ rv,
                                                 const int* __restrict__ sr,
                                                 const int* __restrict__ sc,
                                                 const float* __restrict__ sv,
                                                 const int* __restrict__ cntPB,
                                                 const int* __restrict__ bktBase,
                                                 int2* __restrict__ ent) {
    __shared__ int lds[NC];
    int k = blockIdx.x, tid = threadIdx.x;
    for (int c = tid; c < NC; c += 1024)
        lds[c] = bktBase[c] + cntPB[c * NBLK + k];
    __syncthreads();
    int r0 = k * CHUNK_R, r1 = r0 + CHUNK_R;
    int s0 = k * CHUNK_S, s1 = min(s0 + CHUNK_S, NNZ_S);
    for (int i = r0 + tid; i < r1; i += 1024) {
        int r = rr[i], c = rc[i];
        int v = __float_as_int(rv[i]);
        int pu = atomicAdd(&lds[r >> BSH_U], 1);
        ent[pu] = make_int2(((r & (BROWS_U - 1)) << 17) | c, v);
        int pi = atomicAdd(&lds[NC_U + (c >> BSH_I)], 1);
        ent[pi] = make_int2(((c & (BROWS_I - 1)) << 17) | r, v);
    }
    for (int i = s0 + tid; i < s1; i += 1024) {
        int r = sr[i];
        int ps = atomicAdd(&lds[NC_U + NC_I + (r >> BSH_U)], 1);
        ent[ps] = make_int2(((r & (BROWS_U - 1)) << 17) | sc[i], __float_as_int(sv[i]));
    }
}

// ---- per-bucket counting sort (<=256 local rows) ----
__global__ __launch_bounds__(512) void sort_buckets(const int2* __restrict__ src,
                                                    int2* __restrict__ dst,
                                                    const int* __restrict__ bktBase,
                                                    int* __restrict__ rPu,
                                                    int* __restrict__ rPi,
                                                    int* __restrict__ rPs) {
    int gb = blockIdx.x;
    int* rowptr;
    int brows, lb, nrows;
    if (gb < NC_U)              { rowptr = rPu; brows = BROWS_U; lb = gb;               nrows = NUM_USERS; }
    else if (gb < NC_U + NC_I)  { rowptr = rPi; brows = BROWS_I; lb = gb - NC_U;        nrows = NUM_ITEMS; }
    else                        { rowptr = rPs; brows = BROWS_U; lb = gb - NC_U - NC_I; nrows = NUM_USERS; }
    int t = threadIdx.x;
    __shared__ int cnt[256];
    __shared__ int part[256];
    __shared__ int ofs[256];
    if (t < 256) cnt[t] = 0;
    __syncthreads();
    int b0 = bktBase[gb], b1 = bktBase[gb + 1];
    for (int i = b0 + t; i < b1; i += 512)
        atomicAdd(&cnt[(unsigned)src[i].x >> 17], 1);
    __syncthreads();
    if (t < 256) part[t] = cnt[t];
    __syncthreads();
    for (int off = 1; off < 256; off <<= 1) {
        int v = 0;
        if (t < 256 && t >= off) v = part[t - off];
        __syncthreads();
        if (t < 256) part[t] += v;
        __syncthreads();
    }
    if (t < 256) ofs[t] = part[t] - cnt[t];
    __syncthreads();
    int gr = lb * brows + t;
    if (t < brows && gr < nrows) rowptr[gr] = b0 + ofs[t];
    if (gb == 0 && t == 0) {
        rPu[NUM_USERS] = NNZ_R;
        rPi[NUM_ITEMS] = 2 * NNZ_R;
        rPs[NUM_USERS] = NNZ_TOT;
    }
    __syncthreads();
    for (int i = b0 + t; i < b1; i += 512) {
        int2 v = src[i];
        int lr = (unsigned)v.x >> 17;
        int pos = b0 + atomicAdd(&ofs[lr], 1);
        dst[pos] = make_int2(v.x & 0x1FFFF, v.y);
    }
}

// ---- CSR SpMM: one row per wave, 16 lanes per row-quarter (uint2 = 4 bf16 dims),
//      4 edges per gather instruction, 16 edges in flight; f32 accumulate;
//      butterfly cross-group reduce; fused weighted acc. Two ops per dispatch. ----
struct SpmmOp {
    const int* rowptr;
    const int2* ent;
    const unsigned short* x;    // bf16 rows [*][64]
    unsigned short* out;        // bf16, nullable
    float* acc;                 // f32 (d_out), always valid
    float w;
    int nrows;
};

__global__ __launch_bounds__(256, 4) void spmm2(SpmmOp A, SpmmOp B, int ablocks) {
    bool isA = (int)blockIdx.x < ablocks;
    SpmmOp op = isA ? A : B;
    int bid = isA ? blockIdx.x : blockIdx.x - ablocks;
    int row = bid * 4 + (threadIdx.x >> 6);
    if (row >= op.nrows) return;
    int lane = threadIdx.x & 63;
    int g = lane >> 4;          // edge group 0..3
    int q = lane & 15;          // quarter-row slot: dims 4q..4q+3
    const int2* __restrict__ ent = op.ent;
    const unsigned short* __restrict__ x = op.x;
    int e = op.rowptr[row], end = op.rowptr[row + 1];
    float s0 = 0.f, s1 = 0.f, s2 = 0.f, s3 = 0.f;
    for (; e + 16 <= end; e += 16) {            // 4 edges per group, 16 per wave-iter
        int2 n0 = ent[e + g];
        int2 n1 = ent[e + 4 + g];
        int2 n2 = ent[e + 8 + g];
        int2 n3 = ent[e + 12 + g];
        uint2 r0 = *reinterpret_cast<const uint2*>(x + (size_t)n0.x * DIM + q * 4);
        uint2 r1 = *reinterpret_cast<const uint2*>(x + (size_t)n1.x * DIM + q * 4);
        uint2 r2 = *reinterpret_cast<const uint2*>(x + (size_t)n2.x * DIM + q * 4);
        uint2 r3 = *reinterpret_cast<const uint2*>(x + (size_t)n3.x * DIM + q * 4);
        float v0 = __int_as_float(n0.y), v1 = __int_as_float(n1.y);
        float v2 = __int_as_float(n2.y), v3 = __int_as_float(n3.y);
        s0 += v0 * bflo(r0.x); s1 += v0 * bfhi(r0.x); s2 += v0 * bflo(r0.y); s3 += v0 * bfhi(r0.y);
        s0 += v1 * bflo(r1.x); s1 += v1 * bfhi(r1.x); s2 += v1 * bflo(r1.y); s3 += v1 * bfhi(r1.y);
        s0 += v2 * bflo(r2.x); s1 += v2 * bfhi(r2.x); s2 += v2 * bflo(r2.y); s3 += v2 * bfhi(r2.y);
        s0 += v3 * bflo(r3.x); s1 += v3 * bfhi(r3.x); s2 += v3 * bflo(r3.y); s3 += v3 * bfhi(r3.y);
    }
    for (; e < end; e += 4) {                   // tail: up to 4 edges per step
        if (e + g < end) {
            int2 n = ent[e + g];
            uint2 r = *reinterpret_cast<const uint2*>(x + (size_t)n.x * DIM + q * 4);
            float v = __int_as_float(n.y);
            s0 += v * bflo(r.x); s1 += v * bfhi(r.x);
            s2 += v * bflo(r.y); s3 += v * bfhi(r.y);
        }
    }
    // combine the 4 edge-groups (butterfly over lane bits 4,5)
    s0 += __shfl_xor(s0, 16, 64); s0 += __shfl_xor(s0, 32, 64);
    s1 += __shfl_xor(s1, 16, 64); s1 += __shfl_xor(s1, 32, 64);
    s2 += __shfl_xor(s2, 16, 64); s2 += __shfl_xor(s2, 32, 64);
    s3 += __shfl_xor(s3, 16, 64); s3 += __shfl_xor(s3, 32, 64);
    if (g == 0) {                               // 16 lanes write the full row
        size_t base = (size_t)row * DIM + q * 4;
        if (op.out) {
            uint2 o;
            o.x = (unsigned)f2bf(s0) | ((unsigned)f2bf(s1) << 16);
            o.y = (unsigned)f2bf(s2) | ((unsigned)f2bf(s3) << 16);
            *reinterpret_cast<uint2*>(op.out + base) = o;
        }
        float4* a = reinterpret_cast<float4*>(op.acc + base);
        float4 av = *a;
        av.x += op.w * s0; av.y += op.w * s1; av.z += op.w * s2; av.w += op.w * s3;
        *a = av;
    }
}

// acc init + bf16 copies of inputs (after build; aliases build entries)
__global__ void init_acc(const float* __restrict__ ue, const float* __restrict__ ie,
                         float* __restrict__ accU, float* __restrict__ accI,
                         unsigned short* __restrict__ ueB, unsigned short* __restrict__ ieB,
                         int u4, int i4) {
    const float wu = 0.6f / 4.0f + 0.4f / 3.0f;
    const float wi = 0.25f;
    int i = blockIdx.x * blockDim.x + threadIdx.x;
    int st = gridDim.x * blockDim.x;
    int n4 = u4 + i4;
    for (; i < n4; i += st) {
        if (i < u4) {
            float4 v = reinterpret_cast<const float4*>(ue)[i];
            reinterpret_cast<float4*>(accU)[i] = make_float4(wu * v.x, wu * v.y, wu * v.z, wu * v.w);
            ushort4 b;
            b.x = f2bf(v.x); b.y = f2bf(v.y); b.z = f2bf(v.z); b.w = f2bf(v.w);
            reinterpret_cast<ushort4*>(ueB)[i] = b;
        } else {
            int j = i - u4;
            float4 v = reinterpret_cast<const float4*>(ie)[j];
            reinterpret_cast<float4*>(accI)[j] = make_float4(wi * v.x, wi * v.y, wi * v.z, wi * v.w);
            ushort4 b;
            b.x = f2bf(v.x); b.y = f2bf(v.y); b.z = f2bf(v.z); b.w = f2bf(v.w);
            reinterpret_cast<ushort4*>(ieB)[j] = b;
        }
    }
}

__global__ void finalize_kernel(float* __restrict__ out, int nrows) {
    int row = blockIdx.x * 4 + (threadIdx.x >> 6);
    if (row >= nrows) return;
    int d = threadIdx.x & 63;
    int idx = row * DIM + d;
    float val = out[idx];
    float sq = val * val;
    #pragma unroll
    for (int off = 32; off; off >>= 1) sq += __shfl_xor(sq, off, 64);
    out[idx] = val / fmaxf(sqrtf(sq), 1e-12f);
}

extern "C" void kernel_launch(void* const* d_in, const int* in_sizes, int n_in,
                              void* d_out, int out_size, void* d_ws, size_t ws_size,
                              hipStream_t stream) {
    const float* user_emb = (const float*)d_in[0];
    const float* item_emb = (const float*)d_in[1];
    const float* r_vals   = (const float*)d_in[2];
    const float* s_vals   = (const float*)d_in[3];
    const int*   r_rows   = (const int*)d_in[4];
    const int*   r_cols   = (const int*)d_in[5];
    const int*   s_rows   = (const int*)d_in[6];
    const int*   s_cols   = (const int*)d_in[7];

    const size_t U = (size_t)NUM_USERS * DIM;
    const size_t I = (size_t)NUM_ITEMS * DIM;

    // ---- workspace (~137 MB) ----
    int2* ent_sorted = (int2*)d_ws;                       // NNZ_TOT (67.2 MB), persistent
    char* region2 = (char*)(ent_sorted + NNZ_TOT);        // 67.2 MB union:
    int2* ent_bin = (int2*)region2;                       //   build-time entries
    unsigned short* ueB = (unsigned short*)region2;       //   spmm-time bf16 dense (57.6 MB)
    unsigned short* ieB = ueB + U;
    unsigned short* uA  = ieB + I;
    unsigned short* uB  = uA + U;
    unsigned short* iA  = uB + U;
    unsigned short* iB  = iA + I;
    int* cntPB   = (int*)(region2 + (size_t)NNZ_TOT * 8); // [NC][NBLK] (1.2 MB)
    int* bktBase = cntPB + NPB;                           // NC+1
    int* rPu = bktBase + NC + 1;                          // NUM_USERS+1
    int* rPi = rPu + NUM_USERS + 1;                       // NUM_ITEMS+1
    int* rPs = rPi + NUM_ITEMS + 1;                       // NUM_USERS+1

    float* accU = (float*)d_out;
    float* accI = (float*)d_out + U;

    dim3 blk(256);

    // ---- build: hist -> per-bucket scan -> top scan -> deterministic scatter -> sort ----
    hist_lds<<<NBLK, 1024, 0, stream>>>(r_rows, r_cols, s_rows, cntPB);
    scan_bkt<<<NC, NBLK, 0, stream>>>(cntPB, bktBase);
    scan_top<<<1, 1024, 0, stream>>>(bktBase);
    bin_pass<<<NBLK, 1024, 0, stream>>>(r_rows, r_cols, r_vals, s_rows, s_cols, s_vals,
                                        cntPB, bktBase, ent_bin);
    sort_buckets<<<NC, 512, 0, stream>>>(ent_bin, ent_sorted, bktBase, rPu, rPi, rPs);

    init_acc<<<2048, blk, 0, stream>>>(user_emb, item_emb, accU, accI, ueB, ieB,
                                       (int)(U / 4), (int)(I / 4));

    // ---- 3 bipartite layers, both directions fused per dispatch ----
    const float WU = 0.6f / 4.0f, WI = 0.25f, WS = 0.4f / 3.0f;
    int ub = (NUM_USERS + 3) / 4, ib = (NUM_ITEMS + 3) / 4;

    SpmmOp u1{rPu, ent_sorted, ieB, uA, accU, WU, NUM_USERS};
    SpmmOp i1{rPi, ent_sorted, ueB, iA, accI, WI, NUM_ITEMS};
    spmm2<<<ub + ib, blk, 0, stream>>>(u1, i1, ub);

    SpmmOp u2{rPu, ent_sorted, iA, uB, accU, WU, NUM_USERS};
    SpmmOp i2{rPi, ent_sorted, uA, iB, accI, WI, NUM_ITEMS};
    spmm2<<<ub + ib, blk, 0, stream>>>(u2, i2, ub);

    SpmmOp u3{rPu, ent_sorted, iB, nullptr, accU, WU, NUM_USERS};
    SpmmOp i3{rPi, ent_sorted, uB, nullptr, accI, WI, NUM_ITEMS};
    spmm2<<<ub + ib, blk, 0, stream>>>(u3, i3, ub);

    // ---- 2 social layers (uA dead after layer 2 -> reuse as social ping) ----
    SpmmOp so1{rPs, ent_sorted, ueB, uA, accU, WS, NUM_USERS};
    spmm2<<<ub, blk, 0, stream>>>(so1, so1, ub);
    SpmmOp so2{rPs, ent_sorted, uA, nullptr, accU, WS, NUM_USERS};
    spmm2<<<ub, blk, 0, stream>>>(so2, so2, ub);

    finalize_kernel<<<(NUM_USERS + NUM_ITEMS + 3) / 4, blk, 0, stream>>>(
        (float*)d_out, NUM_USERS + NUM_ITEMS);
}

// Round 14
// 648.424 us; speedup vs baseline: 1.7020x; 1.0880x over previous
//
#include <hip/hip_runtime.h>

constexpr int NUM_USERS = 100000;
constexpr int NUM_ITEMS = 50000;
constexpr int DIM = 64;
constexpr int NNZ_R = 3200000;
constexpr int NNZ_S = 2000000;
constexpr int NNZ_TOT = NNZ_R + NNZ_R + NNZ_S;   // 8.4M entries, one array

constexpr int BSH_U = 8, BROWS_U = 256;     // user/social buckets: 256 rows
constexpr int BSH_I = 7, BROWS_I = 128;     // item buckets: 128 rows
constexpr int NC_U = (NUM_USERS + BROWS_U - 1) / BROWS_U;   // 391
constexpr int NC_I = (NUM_ITEMS + BROWS_I - 1) / BROWS_I;   // 391
constexpr int NC_S = NC_U;                                  // 391
constexpr int NC = NC_U + NC_I + NC_S;                      // 1173
constexpr int NBLK = 256;                   // build blocks, 1/CU
constexpr int NPB = NBLK * NC;
constexpr int CHUNK_R = NNZ_R / NBLK;       // 12500 exact
constexpr int CHUNK_S = (NNZ_S + NBLK - 1) / NBLK;  // 7813

constexpr int SB_EDGES = 4096;              // R sub-batch: 4096 edges -> 8192 entries
constexpr int SB_PAIRS = 8192;

__device__ __forceinline__ float bf2f(unsigned short u) {
    return __uint_as_float((unsigned)u << 16);
}
__device__ __forceinline__ unsigned short f2bf(float f) {   // round-to-nearest-even
    unsigned u = __float_as_uint(f);
    return (unsigned short)((u + 0x7FFFu + ((u >> 16) & 1u)) >> 16);
}
__device__ __forceinline__ float bflo(unsigned r) { return __uint_as_float(r << 16); }
__device__ __forceinline__ float bfhi(unsigned r) { return __uint_as_float(r & 0xFFFF0000u); }

// ---- pass A: LDS histogram; per-(block,bucket) counts BUCKET-MAJOR ----
__global__ __launch_bounds__(1024) void hist_lds(const int* __restrict__ rr,
                                                 const int* __restrict__ rc,
                                                 const int* __restrict__ sr,
                                                 int* __restrict__ cntPB /* [NC][NBLK] */) {
    __shared__ int lds[NC];
    int k = blockIdx.x, tid = threadIdx.x;
    for (int c = tid; c < NC; c += 1024) lds[c] = 0;
    __syncthreads();
    int r0 = k * CHUNK_R, r1 = r0 + CHUNK_R;
    int s0 = k * CHUNK_S, s1 = min(s0 + CHUNK_S, NNZ_S);
    for (int i = r0 + tid; i < r1; i += 1024) {
        atomicAdd(&lds[rr[i] >> BSH_U], 1);
        atomicAdd(&lds[NC_U + (rc[i] >> BSH_I)], 1);
    }
    for (int i = s0 + tid; i < s1; i += 1024)
        atomicAdd(&lds[NC_U + NC_I + (sr[i] >> BSH_U)], 1);
    __syncthreads();
    for (int c = tid; c < NC; c += 1024) cntPB[c * NBLK + k] = lds[c];
}

// ---- per-bucket exscan over NBLK block-counts (one block per bucket) ----
__global__ __launch_bounds__(NBLK) void scan_bkt(int* __restrict__ cntPB,
                                                 int* __restrict__ bktTot) {
    int c = blockIdx.x, t = threadIdx.x;
    __shared__ int sh[NBLK];
    int v = cntPB[c * NBLK + t];
    sh[t] = v;
    __syncthreads();
    for (int off = 1; off < NBLK; off <<= 1) {
        int u = (t >= off) ? sh[t - off] : 0;
        __syncthreads();
        sh[t] += u;
        __syncthreads();
    }
    cntPB[c * NBLK + t] = sh[t] - v;
    if (t == NBLK - 1) bktTot[c] = sh[t];
}

// ---- tiny top-level exscan over NC bucket totals ----
__global__ __launch_bounds__(1024) void scan_top(int* __restrict__ B /* NC+1 */) {
    __shared__ int part[1024];
    int t = threadIdx.x;
    const int chunk = (NC + 1023) >> 10;
    int lo = t * chunk, hi = min(lo + chunk, NC);
    int s = 0;
    for (int i = lo; i < hi; ++i) s += B[i];
    part[t] = s;
    __syncthreads();
    for (int off = 1; off < 1024; off <<= 1) {
        int v = (t >= off) ? part[t - off] : 0;
        __syncthreads();
        part[t] += v;
        __syncthreads();
    }
    int excl = (t == 0) ? 0 : part[t - 1];
    for (int i = lo; i < hi; ++i) {
        int v = B[i];
        B[i] = excl;
        excl += v;
    }
    if (t == 1023) B[NC] = part[1023];
}

// ---- pass B: LDS-staged sub-batch sort, then wave-coalesced contiguous writes.
//      Fixes the per-wave-instruction sector-padding write amp (64 lanes used to
//      write 64 random 8B frontiers; now 64 consecutive staged slots). ----
__global__ __launch_bounds__(1024) void bin_pass(const int* __restrict__ rr,
                                                 const int* __restrict__ rc,
                                                 const float* __restrict__ rv,
                                                 const int* __restrict__ sr,
                                                 const int* __restrict__ sc,
                                                 const float* __restrict__ sv,
                                                 const int* __restrict__ cntPB,
                                                 const int* __restrict__ bktBase,
                                                 int2* __restrict__ ent) {
    __shared__ int cur[NC];       // global frontier per bucket (this block)
    __shared__ int cnt[NC];       // sub-batch histogram
    __shared__ int lstart[NC];    // sub-batch exclusive prefix
    __shared__ int lcur[NC];      // sub-batch scatter cursor
    __shared__ int part[1024];
    __shared__ int2 stage[SB_PAIRS];
    __shared__ int gaddr[SB_PAIRS];
    int k = blockIdx.x, tid = threadIdx.x;
    for (int c = tid; c < NC; c += 1024)
        cur[c] = bktBase[c] + cntPB[c * NBLK + k];

    // ---- R edges: CHUNK_R in sub-batches of SB_EDGES (each -> 2 entries) ----
    int r0 = k * CHUNK_R;
    for (int sb = 0; sb < CHUNK_R; sb += SB_EDGES) {
        int nE = min(SB_EDGES, CHUNK_R - sb);
        int base = r0 + sb;
        for (int c = tid; c < NC; c += 1024) { cnt[c] = 0; lcur[c] = 0; }
        __syncthreads();
        for (int i = tid; i < nE; i += 1024) {
            atomicAdd(&cnt[rr[base + i] >> BSH_U], 1);
            atomicAdd(&cnt[NC_U + (rc[base + i] >> BSH_I)], 1);
        }
        __syncthreads();
        // block exscan over NC (2 counters per thread)
        int o0 = 2 * tid, o1 = 2 * tid + 1;
        int a = (o0 < NC) ? cnt[o0] : 0;
        int b = (o1 < NC) ? cnt[o1] : 0;
        part[tid] = a + b;
        __syncthreads();
        for (int off = 1; off < 1024; off <<= 1) {
            int v = (tid >= off) ? part[tid - off] : 0;
            __syncthreads();
            part[tid] += v;
            __syncthreads();
        }
        int ex = (tid == 0) ? 0 : part[tid - 1];
        if (o0 < NC) lstart[o0] = ex;
        if (o1 < NC) lstart[o1] = ex + a;
        __syncthreads();
        // scatter into LDS staging (+ global address per slot)
        for (int i = tid; i < nE; i += 1024) {
            int r = rr[base + i], c = rc[base + i];
            int v = __float_as_int(rv[base + i]);
            int cu_ = r >> BSH_U;
            int j = atomicAdd(&lcur[cu_], 1);
            int lp = lstart[cu_] + j;
            stage[lp] = make_int2(((r & (BROWS_U - 1)) << 17) | c, v);
            gaddr[lp] = cur[cu_] + j;
            int ci_ = NC_U + (c >> BSH_I);
            int j2 = atomicAdd(&lcur[ci_], 1);
            int lp2 = lstart[ci_] + j2;
            stage[lp2] = make_int2(((c & (BROWS_I - 1)) << 17) | r, v);
            gaddr[lp2] = cur[ci_] + j2;
        }
        __syncthreads();
        // coalesced write: consecutive lanes -> consecutive slots -> contiguous runs
        int nP = 2 * nE;
        for (int s = tid; s < nP; s += 1024)
            ent[gaddr[s]] = stage[s];
        for (int c = tid; c < NC; c += 1024) cur[c] += cnt[c];
        __syncthreads();
    }

    // ---- S edges: one sub-batch of <= SB_PAIRS edges (1 entry each) ----
    int s0 = k * CHUNK_S, sEnd = min(s0 + CHUNK_S, NNZ_S);
    for (int sb = s0; sb < sEnd; sb += SB_PAIRS) {
        int nE = min(SB_PAIRS, sEnd - sb);
        for (int c = tid; c < NC; c += 1024) { cnt[c] = 0; lcur[c] = 0; }
        __syncthreads();
        for (int i = tid; i < nE; i += 1024)
            atomicAdd(&cnt[NC_U + NC_I + (sr[sb + i] >> BSH_U)], 1);
        __syncthreads();
        int o0 = 2 * tid, o1 = 2 * tid + 1;
        int a = (o0 < NC) ? cnt[o0] : 0;
        int b = (o1 < NC) ? cnt[o1] : 0;
        part[tid] = a + b;
        __syncthreads();
        for (int off = 1; off < 1024; off <<= 1) {
            int v = (tid >= off) ? part[tid - off] : 0;
            __syncthreads();
            part[tid] += v;
            __syncthreads();
        }
        int ex = (tid == 0) ? 0 : part[tid - 1];
        if (o0 < NC) lstart[o0] = ex;
        if (o1 < NC) lstart[o1] = ex + a;
        __syncthreads();
        for (int i = tid; i < nE; i += 1024) {
            int r = sr[sb + i];
            int cs_ = NC_U + NC_I + (r >> BSH_U);
            int j = atomicAdd(&lcur[cs_], 1);
            int lp = lstart[cs_] + j;
            stage[lp] = make_int2(((r & (BROWS_U - 1)) << 17) | sc[sb + i],
                                  __float_as_int(sv[sb + i]));
            gaddr[lp] = cur[cs_] + j;
        }
        __syncthreads();
        for (int s = tid; s < nE; s += 1024)
            ent[gaddr[s]] = stage[s];
        for (int c = tid; c < NC; c += 1024) cur[c] += cnt[c];
        __syncthreads();
    }
}

// ---- per-bucket counting sort (<=256 local rows) ----
__global__ __launch_bounds__(512) void sort_buckets(const int2* __restrict__ src,
                                                    int2* __restrict__ dst,
                                                    const int* __restrict__ bktBase,
                                                    int* __restrict__ rPu,
                                                    int* __restrict__ rPi,
                                                    int* __restrict__ rPs) {
    int gb = blockIdx.x;
    int* rowptr;
    int brows, lb, nrows;
    if (gb < NC_U)              { rowptr = rPu; brows = BROWS_U; lb = gb;               nrows = NUM_USERS; }
    else if (gb < NC_U + NC_I)  { rowptr = rPi; brows = BROWS_I; lb = gb - NC_U;        nrows = NUM_ITEMS; }
    else                        { rowptr = rPs; brows = BROWS_U; lb = gb - NC_U - NC_I; nrows = NUM_USERS; }
    int t = threadIdx.x;
    __shared__ int cnt[256];
    __shared__ int part[256];
    __shared__ int ofs[256];
    if (t < 256) cnt[t] = 0;
    __syncthreads();
    int b0 = bktBase[gb], b1 = bktBase[gb + 1];
    for (int i = b0 + t; i < b1; i += 512)
        atomicAdd(&cnt[(unsigned)src[i].x >> 17], 1);
    __syncthreads();
    if (t < 256) part[t] = cnt[t];
    __syncthreads();
    for (int off = 1; off < 256; off <<= 1) {
        int v = 0;
        if (t < 256 && t >= off) v = part[t - off];
        __syncthreads();
        if (t < 256) part[t] += v;
        __syncthreads();
    }
    if (t < 256) ofs[t] = part[t] - cnt[t];
    __syncthreads();
    int gr = lb * brows + t;
    if (t < brows && gr < nrows) rowptr[gr] = b0 + ofs[t];
    if (gb == 0 && t == 0) {
        rPu[NUM_USERS] = NNZ_R;
        rPi[NUM_ITEMS] = 2 * NNZ_R;
        rPs[NUM_USERS] = NNZ_TOT;
    }
    __syncthreads();
    for (int i = b0 + t; i < b1; i += 512) {
        int2 v = src[i];
        int lr = (unsigned)v.x >> 17;
        int pos = b0 + atomicAdd(&ofs[lr], 1);
        dst[pos] = make_int2(v.x & 0x1FFFF, v.y);
    }
}

// ---- CSR SpMM: one row per wave, 16 lanes per row-quarter (uint2 = 4 bf16 dims),
//      4 edges per gather instruction, 16 edges in flight; f32 accumulate;
//      butterfly cross-group reduce; fused weighted acc. Two ops per dispatch. ----
struct SpmmOp {
    const int* rowptr;
    const int2* ent;
    const unsigned short* x;    // bf16 rows [*][64]
    unsigned short* out;        // bf16, nullable
    float* acc;                 // f32 (d_out), always valid
    float w;
    int nrows;
};

__global__ __launch_bounds__(256, 4) void spmm2(SpmmOp A, SpmmOp B, int ablocks) {
    bool isA = (int)blockIdx.x < ablocks;
    SpmmOp op = isA ? A : B;
    int bid = isA ? blockIdx.x : blockIdx.x - ablocks;
    int row = bid * 4 + (threadIdx.x >> 6);
    if (row >= op.nrows) return;
    int lane = threadIdx.x & 63;
    int g = lane >> 4;          // edge group 0..3
    int q = lane & 15;          // quarter-row slot: dims 4q..4q+3
    const int2* __restrict__ ent = op.ent;
    const unsigned short* __restrict__ x = op.x;
    int e = op.rowptr[row], end = op.rowptr[row + 1];
    float s0 = 0.f, s1 = 0.f, s2 = 0.f, s3 = 0.f;
    for (; e + 16 <= end; e += 16) {            // 4 edges per group, 16 per wave-iter
        int2 n0 = ent[e + g];
        int2 n1 = ent[e + 4 + g];
        int2 n2 = ent[e + 8 + g];
        int2 n3 = ent[e + 12 + g];
        uint2 r0 = *reinterpret_cast<const uint2*>(x + (size_t)n0.x * DIM + q * 4);
        uint2 r1 = *reinterpret_cast<const uint2*>(x + (size_t)n1.x * DIM + q * 4);
        uint2 r2 = *reinterpret_cast<const uint2*>(x + (size_t)n2.x * DIM + q * 4);
        uint2 r3 = *reinterpret_cast<const uint2*>(x + (size_t)n3.x * DIM + q * 4);
        float v0 = __int_as_float(n0.y), v1 = __int_as_float(n1.y);
        float v2 = __int_as_float(n2.y), v3 = __int_as_float(n3.y);
        s0 += v0 * bflo(r0.x); s1 += v0 * bfhi(r0.x); s2 += v0 * bflo(r0.y); s3 += v0 * bfhi(r0.y);
        s0 += v1 * bflo(r1.x); s1 += v1 * bfhi(r1.x); s2 += v1 * bflo(r1.y); s3 += v1 * bfhi(r1.y);
        s0 += v2 * bflo(r2.x); s1 += v2 * bfhi(r2.x); s2 += v2 * bflo(r2.y); s3 += v2 * bfhi(r2.y);
        s0 += v3 * bflo(r3.x); s1 += v3 * bfhi(r3.x); s2 += v3 * bflo(r3.y); s3 += v3 * bfhi(r3.y);
    }
    for (; e < end; e += 4) {                   // tail: up to 4 edges per step
        if (e + g < end) {
            int2 n = ent[e + g];
            uint2 r = *reinterpret_cast<const uint2*>(x + (size_t)n.x * DIM + q * 4);
            float v = __int_as_float(n.y);
            s0 += v * bflo(r.x); s1 += v * bfhi(r.x);
            s2 += v * bflo(r.y); s3 += v * bfhi(r.y);
        }
    }
    // combine the 4 edge-groups (butterfly over lane bits 4,5)
    s0 += __shfl_xor(s0, 16, 64); s0 += __shfl_xor(s0, 32, 64);
    s1 += __shfl_xor(s1, 16, 64); s1 += __shfl_xor(s1, 32, 64);
    s2 += __shfl_xor(s2, 16, 64); s2 += __shfl_xor(s2, 32, 64);
    s3 += __shfl_xor(s3, 16, 64); s3 += __shfl_xor(s3, 32, 64);
    if (g == 0) {                               // 16 lanes write the full row
        size_t base = (size_t)row * DIM + q * 4;
        if (op.out) {
            uint2 o;
            o.x = (unsigned)f2bf(s0) | ((unsigned)f2bf(s1) << 16);
            o.y = (unsigned)f2bf(s2) | ((unsigned)f2bf(s3) << 16);
            *reinterpret_cast<uint2*>(op.out + base) = o;
        }
        float4* a = reinterpret_cast<float4*>(op.acc + base);
        float4 av = *a;
        av.x += op.w * s0; av.y += op.w * s1; av.z += op.w * s2; av.w += op.w * s3;
        *a = av;
    }
}

// acc init + bf16 copies of inputs (after build; aliases build entries)
__global__ void init_acc(const float* __restrict__ ue, const float* __restrict__ ie,
                         float* __restrict__ accU, float* __restrict__ accI,
                         unsigned short* __restrict__ ueB, unsigned short* __restrict__ ieB,
                         int u4, int i4) {
    const float wu = 0.6f / 4.0f + 0.4f / 3.0f;
    const float wi = 0.25f;
    int i = blockIdx.x * blockDim.x + threadIdx.x;
    int st = gridDim.x * blockDim.x;
    int n4 = u4 + i4;
    for (; i < n4; i += st) {
        if (i < u4) {
            float4 v = reinterpret_cast<const float4*>(ue)[i];
            reinterpret_cast<float4*>(accU)[i] = make_float4(wu * v.x, wu * v.y, wu * v.z, wu * v.w);
            ushort4 b;
            b.x = f2bf(v.x); b.y = f2bf(v.y); b.z = f2bf(v.z); b.w = f2bf(v.w);
            reinterpret_cast<ushort4*>(ueB)[i] = b;
        } else {
            int j = i - u4;
            float4 v = reinterpret_cast<const float4*>(ie)[j];
            reinterpret_cast<float4*>(accI)[j] = make_float4(wi * v.x, wi * v.y, wi * v.z, wi * v.w);
            ushort4 b;
            b.x = f2bf(v.x); b.y = f2bf(v.y); b.z = f2bf(v.z); b.w = f2bf(v.w);
            reinterpret_cast<ushort4*>(ieB)[j] = b;
        }
    }
}

__global__ void finalize_kernel(float* __restrict__ out, int nrows) {
    int row = blockIdx.x * 4 + (threadIdx.x >> 6);
    if (row >= nrows) return;
    int d = threadIdx.x & 63;
    int idx = row * DIM + d;
    float val = out[idx];
    float sq = val * val;
    #pragma unroll
    for (int off = 32; off; off >>= 1) sq += __shfl_xor(sq, off, 64);
    out[idx] = val / fmaxf(sqrtf(sq), 1e-12f);
}

extern "C" void kernel_launch(void* const* d_in, const int* in_sizes, int n_in,
                              void* d_out, int out_size, void* d_ws, size_t ws_size,
                              hipStream_t stream) {
    const float* user_emb = (const float*)d_in[0];
    const float* item_emb = (const float*)d_in[1];
    const float* r_vals   = (const float*)d_in[2];
    const float* s_vals   = (const float*)d_in[3];
    const int*   r_rows   = (const int*)d_in[4];
    const int*   r_cols   = (const int*)d_in[5];
    const int*   s_rows   = (const int*)d_in[6];
    const int*   s_cols   = (const int*)d_in[7];

    const size_t U = (size_t)NUM_USERS * DIM;
    const size_t I = (size_t)NUM_ITEMS * DIM;

    // ---- workspace (~137 MB) ----
    int2* ent_sorted = (int2*)d_ws;                       // NNZ_TOT (67.2 MB), persistent
    char* region2 = (char*)(ent_sorted + NNZ_TOT);        // 67.2 MB union:
    int2* ent_bin = (int2*)region2;                       //   build-time entries
    unsigned short* ueB = (unsigned short*)region2;       //   spmm-time bf16 dense (57.6 MB)
    unsigned short* ieB = ueB + U;
    unsigned short* uA  = ieB + I;
    unsigned short* uB  = uA + U;
    unsigned short* iA  = uB + U;
    unsigned short* iB  = iA + I;
    int* cntPB   = (int*)(region2 + (size_t)NNZ_TOT * 8); // [NC][NBLK] (1.2 MB)
    int* bktBase = cntPB + NPB;                           // NC+1
    int* rPu = bktBase + NC + 1;                          // NUM_USERS+1
    int* rPi = rPu + NUM_USERS + 1;                       // NUM_ITEMS+1
    int* rPs = rPi + NUM_ITEMS + 1;                       // NUM_USERS+1

    float* accU = (float*)d_out;
    float* accI = (float*)d_out + U;

    dim3 blk(256);

    // ---- build: hist -> per-bucket scan -> top scan -> staged scatter -> sort ----
    hist_lds<<<NBLK, 1024, 0, stream>>>(r_rows, r_cols, s_rows, cntPB);
    scan_bkt<<<NC, NBLK, 0, stream>>>(cntPB, bktBase);
    scan_top<<<1, 1024, 0, stream>>>(bktBase);
    bin_pass<<<NBLK, 1024, 0, stream>>>(r_rows, r_cols, r_vals, s_rows, s_cols, s_vals,
                                        cntPB, bktBase, ent_bin);
    sort_buckets<<<NC, 512, 0, stream>>>(ent_bin, ent_sorted, bktBase, rPu, rPi, rPs);

    init_acc<<<2048, blk, 0, stream>>>(user_emb, item_emb, accU, accI, ueB, ieB,
                                       (int)(U / 4), (int)(I / 4));

    // ---- 3 bipartite layers, both directions fused per dispatch ----
    const float WU = 0.6f / 4.0f, WI = 0.25f, WS = 0.4f / 3.0f;
    int ub = (NUM_USERS + 3) / 4, ib = (NUM_ITEMS + 3) / 4;

    SpmmOp u1{rPu, ent_sorted, ieB, uA, accU, WU, NUM_USERS};
    SpmmOp i1{rPi, ent_sorted, ueB, iA, accI, WI, NUM_ITEMS};
    spmm2<<<ub + ib, blk, 0, stream>>>(u1, i1, ub);

    SpmmOp u2{rPu, ent_sorted, iA, uB, accU, WU, NUM_USERS};
    SpmmOp i2{rPi, ent_sorted, uA, iB, accI, WI, NUM_ITEMS};
    spmm2<<<ub + ib, blk, 0, stream>>>(u2, i2, ub);

    SpmmOp u3{rPu, ent_sorted, iB, nullptr, accU, WU, NUM_USERS};
    SpmmOp i3{rPi, ent_sorted, uB, nullptr, accI, WI, NUM_ITEMS};
    spmm2<<<ub + ib, blk, 0, stream>>>(u3, i3, ub);

    // ---- 2 social layers (uA dead after layer 2 -> reuse as social ping) ----
    SpmmOp so1{rPs, ent_sorted, ueB, uA, accU, WS, NUM_USERS};
    spmm2<<<ub, blk, 0, stream>>>(so1, so1, ub);
    SpmmOp so2{rPs, ent_sorted, uA, nullptr, accU, WS, NUM_USERS};
    spmm2<<<ub, blk, 0, stream>>>(so2, so2, ub);

    finalize_kernel<<<(NUM_USERS + NUM_ITEMS + 3) / 4, blk, 0, stream>>>(
        (float*)d_out, NUM_USERS + NUM_ITEMS);
}

// Round 15
// 643.431 us; speedup vs baseline: 1.7152x; 1.0078x over previous
//
#include <hip/hip_runtime.h>

constexpr int NUM_USERS = 100000;
constexpr int NUM_ITEMS = 50000;
constexpr int DIM = 64;
constexpr int NNZ_R = 3200000;
constexpr int NNZ_S = 2000000;
constexpr int NNZ_TOT = NNZ_R + NNZ_R + NNZ_S;   // 8.4M entries, one array

constexpr int BSH_U = 8, BROWS_U = 256;     // user/social buckets: 256 rows
constexpr int BSH_I = 7, BROWS_I = 128;     // item buckets: 128 rows
constexpr int NC_U = (NUM_USERS + BROWS_U - 1) / BROWS_U;   // 391
constexpr int NC_I = (NUM_ITEMS + BROWS_I - 1) / BROWS_I;   // 391
constexpr int NC_S = NC_U;                                  // 391
constexpr int NC = NC_U + NC_I + NC_S;                      // 1173
constexpr int NBLK = 256;                   // build blocks, 1/CU
constexpr int NPB = NBLK * NC;
constexpr int CHUNK_R = NNZ_R / NBLK;       // 12500 exact
constexpr int CHUNK_S = (NNZ_S + NBLK - 1) / NBLK;  // 7813

constexpr int SB_EDGES = 4096;              // R sub-batch: 4096 edges -> 8192 entries
constexpr int SB_PAIRS = 8192;

__device__ __forceinline__ float bf2f(unsigned short u) {
    return __uint_as_float((unsigned)u << 16);
}
__device__ __forceinline__ unsigned short f2bf(float f) {   // round-to-nearest-even
    unsigned u = __float_as_uint(f);
    return (unsigned short)((u + 0x7FFFu + ((u >> 16) & 1u)) >> 16);
}
__device__ __forceinline__ float bflo(unsigned r) { return __uint_as_float(r << 16); }
__device__ __forceinline__ float bfhi(unsigned r) { return __uint_as_float(r & 0xFFFF0000u); }

// ---- pass A: LDS histogram; per-(block,bucket) counts BUCKET-MAJOR ----
__global__ __launch_bounds__(1024) void hist_lds(const int* __restrict__ rr,
                                                 const int* __restrict__ rc,
                                                 const int* __restrict__ sr,
                                                 int* __restrict__ cntPB /* [NC][NBLK] */) {
    __shared__ int lds[NC];
    int k = blockIdx.x, tid = threadIdx.x;
    for (int c = tid; c < NC; c += 1024) lds[c] = 0;
    __syncthreads();
    int r0 = k * CHUNK_R, r1 = r0 + CHUNK_R;
    int s0 = k * CHUNK_S, s1 = min(s0 + CHUNK_S, NNZ_S);
    for (int i = r0 + tid; i < r1; i += 1024) {
        atomicAdd(&lds[rr[i] >> BSH_U], 1);
        atomicAdd(&lds[NC_U + (rc[i] >> BSH_I)], 1);
    }
    for (int i = s0 + tid; i < s1; i += 1024)
        atomicAdd(&lds[NC_U + NC_I + (sr[i] >> BSH_U)], 1);
    __syncthreads();
    for (int c = tid; c < NC; c += 1024) cntPB[c * NBLK + k] = lds[c];
}

// ---- per-bucket exscan over NBLK block-counts (one block per bucket) ----
__global__ __launch_bounds__(NBLK) void scan_bkt(int* __restrict__ cntPB,
                                                 int* __restrict__ bktTot) {
    int c = blockIdx.x, t = threadIdx.x;
    __shared__ int sh[NBLK];
    int v = cntPB[c * NBLK + t];
    sh[t] = v;
    __syncthreads();
    for (int off = 1; off < NBLK; off <<= 1) {
        int u = (t >= off) ? sh[t - off] : 0;
        __syncthreads();
        sh[t] += u;
        __syncthreads();
    }
    cntPB[c * NBLK + t] = sh[t] - v;
    if (t == NBLK - 1) bktTot[c] = sh[t];
}

// ---- tiny top-level exscan over NC bucket totals ----
__global__ __launch_bounds__(1024) void scan_top(int* __restrict__ B /* NC+1 */) {
    __shared__ int part[1024];
    int t = threadIdx.x;
    const int chunk = (NC + 1023) >> 10;
    int lo = t * chunk, hi = min(lo + chunk, NC);
    int s = 0;
    for (int i = lo; i < hi; ++i) s += B[i];
    part[t] = s;
    __syncthreads();
    for (int off = 1; off < 1024; off <<= 1) {
        int v = (t >= off) ? part[t - off] : 0;
        __syncthreads();
        part[t] += v;
        __syncthreads();
    }
    int excl = (t == 0) ? 0 : part[t - 1];
    for (int i = lo; i < hi; ++i) {
        int v = B[i];
        B[i] = excl;
        excl += v;
    }
    if (t == 1023) B[NC] = part[1023];
}

// ---- pass B: LDS-staged sub-batch sort, then wave-coalesced contiguous writes ----
__global__ __launch_bounds__(1024) void bin_pass(const int* __restrict__ rr,
                                                 const int* __restrict__ rc,
                                                 const float* __restrict__ rv,
                                                 const int* __restrict__ sr,
                                                 const int* __restrict__ sc,
                                                 const float* __restrict__ sv,
                                                 const int* __restrict__ cntPB,
                                                 const int* __restrict__ bktBase,
                                                 int2* __restrict__ ent) {
    __shared__ int cur[NC];       // global frontier per bucket (this block)
    __shared__ int cnt[NC];       // sub-batch histogram
    __shared__ int lstart[NC];    // sub-batch exclusive prefix
    __shared__ int lcur[NC];      // sub-batch scatter cursor
    __shared__ int part[1024];
    __shared__ int2 stage[SB_PAIRS];
    __shared__ int gaddr[SB_PAIRS];
    int k = blockIdx.x, tid = threadIdx.x;
    for (int c = tid; c < NC; c += 1024)
        cur[c] = bktBase[c] + cntPB[c * NBLK + k];

    // ---- R edges: CHUNK_R in sub-batches of SB_EDGES (each -> 2 entries) ----
    int r0 = k * CHUNK_R;
    for (int sb = 0; sb < CHUNK_R; sb += SB_EDGES) {
        int nE = min(SB_EDGES, CHUNK_R - sb);
        int base = r0 + sb;
        for (int c = tid; c < NC; c += 1024) { cnt[c] = 0; lcur[c] = 0; }
        __syncthreads();
        for (int i = tid; i < nE; i += 1024) {
            atomicAdd(&cnt[rr[base + i] >> BSH_U], 1);
            atomicAdd(&cnt[NC_U + (rc[base + i] >> BSH_I)], 1);
        }
        __syncthreads();
        int o0 = 2 * tid, o1 = 2 * tid + 1;
        int a = (o0 < NC) ? cnt[o0] : 0;
        int b = (o1 < NC) ? cnt[o1] : 0;
        part[tid] = a + b;
        __syncthreads();
        for (int off = 1; off < 1024; off <<= 1) {
            int v = (tid >= off) ? part[tid - off] : 0;
            __syncthreads();
            part[tid] += v;
            __syncthreads();
        }
        int ex = (tid == 0) ? 0 : part[tid - 1];
        if (o0 < NC) lstart[o0] = ex;
        if (o1 < NC) lstart[o1] = ex + a;
        __syncthreads();
        for (int i = tid; i < nE; i += 1024) {
            int r = rr[base + i], c = rc[base + i];
            int v = __float_as_int(rv[base + i]);
            int cu_ = r >> BSH_U;
            int j = atomicAdd(&lcur[cu_], 1);
            int lp = lstart[cu_] + j;
            stage[lp] = make_int2(((r & (BROWS_U - 1)) << 17) | c, v);
            gaddr[lp] = cur[cu_] + j;
            int ci_ = NC_U + (c >> BSH_I);
            int j2 = atomicAdd(&lcur[ci_], 1);
            int lp2 = lstart[ci_] + j2;
            stage[lp2] = make_int2(((c & (BROWS_I - 1)) << 17) | r, v);
            gaddr[lp2] = cur[ci_] + j2;
        }
        __syncthreads();
        int nP = 2 * nE;
        for (int s = tid; s < nP; s += 1024)
            ent[gaddr[s]] = stage[s];
        for (int c = tid; c < NC; c += 1024) cur[c] += cnt[c];
        __syncthreads();
    }

    // ---- S edges ----
    int s0 = k * CHUNK_S, sEnd = min(s0 + CHUNK_S, NNZ_S);
    for (int sb = s0; sb < sEnd; sb += SB_PAIRS) {
        int nE = min(SB_PAIRS, sEnd - sb);
        for (int c = tid; c < NC; c += 1024) { cnt[c] = 0; lcur[c] = 0; }
        __syncthreads();
        for (int i = tid; i < nE; i += 1024)
            atomicAdd(&cnt[NC_U + NC_I + (sr[sb + i] >> BSH_U)], 1);
        __syncthreads();
        int o0 = 2 * tid, o1 = 2 * tid + 1;
        int a = (o0 < NC) ? cnt[o0] : 0;
        int b = (o1 < NC) ? cnt[o1] : 0;
        part[tid] = a + b;
        __syncthreads();
        for (int off = 1; off < 1024; off <<= 1) {
            int v = (tid >= off) ? part[tid - off] : 0;
            __syncthreads();
            part[tid] += v;
            __syncthreads();
        }
        int ex = (tid == 0) ? 0 : part[tid - 1];
        if (o0 < NC) lstart[o0] = ex;
        if (o1 < NC) lstart[o1] = ex + a;
        __syncthreads();
        for (int i = tid; i < nE; i += 1024) {
            int r = sr[sb + i];
            int cs_ = NC_U + NC_I + (r >> BSH_U);
            int j = atomicAdd(&lcur[cs_], 1);
            int lp = lstart[cs_] + j;
            stage[lp] = make_int2(((r & (BROWS_U - 1)) << 17) | sc[sb + i],
                                  __float_as_int(sv[sb + i]));
            gaddr[lp] = cur[cs_] + j;
        }
        __syncthreads();
        for (int s = tid; s < nE; s += 1024)
            ent[gaddr[s]] = stage[s];
        for (int c = tid; c < NC; c += 1024) cur[c] += cnt[c];
        __syncthreads();
    }
}

// ---- per-bucket counting sort (<=256 local rows) ----
__global__ __launch_bounds__(512) void sort_buckets(const int2* __restrict__ src,
                                                    int2* __restrict__ dst,
                                                    const int* __restrict__ bktBase,
                                                    int* __restrict__ rPu,
                                                    int* __restrict__ rPi,
                                                    int* __restrict__ rPs) {
    int gb = blockIdx.x;
    int* rowptr;
    int brows, lb, nrows;
    if (gb < NC_U)              { rowptr = rPu; brows = BROWS_U; lb = gb;               nrows = NUM_USERS; }
    else if (gb < NC_U + NC_I)  { rowptr = rPi; brows = BROWS_I; lb = gb - NC_U;        nrows = NUM_ITEMS; }
    else                        { rowptr = rPs; brows = BROWS_U; lb = gb - NC_U - NC_I; nrows = NUM_USERS; }
    int t = threadIdx.x;
    __shared__ int cnt[256];
    __shared__ int part[256];
    __shared__ int ofs[256];
    if (t < 256) cnt[t] = 0;
    __syncthreads();
    int b0 = bktBase[gb], b1 = bktBase[gb + 1];
    for (int i = b0 + t; i < b1; i += 512)
        atomicAdd(&cnt[(unsigned)src[i].x >> 17], 1);
    __syncthreads();
    if (t < 256) part[t] = cnt[t];
    __syncthreads();
    for (int off = 1; off < 256; off <<= 1) {
        int v = 0;
        if (t < 256 && t >= off) v = part[t - off];
        __syncthreads();
        if (t < 256) part[t] += v;
        __syncthreads();
    }
    if (t < 256) ofs[t] = part[t] - cnt[t];
    __syncthreads();
    int gr = lb * brows + t;
    if (t < brows && gr < nrows) rowptr[gr] = b0 + ofs[t];
    if (gb == 0 && t == 0) {
        rPu[NUM_USERS] = NNZ_R;
        rPi[NUM_ITEMS] = 2 * NNZ_R;
        rPs[NUM_USERS] = NNZ_TOT;
    }
    __syncthreads();
    for (int i = b0 + t; i < b1; i += 512) {
        int2 v = src[i];
        int lr = (unsigned)v.x >> 17;
        int pos = b0 + atomicAdd(&ofs[lr], 1);
        dst[pos] = make_int2(v.x & 0x1FFFF, v.y);
    }
}

// ---- CSR SpMM: one row per wave, 16 lanes per row-quarter, 4 edges in flight
//      per lane in BOTH main loop and the single predicated 16-wide tail step. ----
struct SpmmOp {
    const int* rowptr;
    const int2* ent;
    const unsigned short* x;    // bf16 rows [*][64]
    unsigned short* out;        // bf16, nullable
    float* acc;                 // f32 (d_out), always valid
    float w;
    int nrows;
};

__global__ __launch_bounds__(256, 4) void spmm2(SpmmOp A, SpmmOp B, int ablocks) {
    bool isA = (int)blockIdx.x < ablocks;
    SpmmOp op = isA ? A : B;
    int bid = isA ? blockIdx.x : blockIdx.x - ablocks;
    int row = bid * 4 + (threadIdx.x >> 6);
    if (row >= op.nrows) return;
    int lane = threadIdx.x & 63;
    int g = lane >> 4;          // edge group 0..3
    int q = lane & 15;          // quarter-row slot: dims 4q..4q+3
    const int2* __restrict__ ent = op.ent;
    const unsigned short* __restrict__ x = op.x;
    int e = op.rowptr[row], end = op.rowptr[row + 1];
    float s0 = 0.f, s1 = 0.f, s2 = 0.f, s3 = 0.f;
    for (; e + 16 <= end; e += 16) {            // 4 edges per group, 16 per wave-iter
        int2 n0 = ent[e + g];
        int2 n1 = ent[e + 4 + g];
        int2 n2 = ent[e + 8 + g];
        int2 n3 = ent[e + 12 + g];
        uint2 r0 = *reinterpret_cast<const uint2*>(x + (size_t)n0.x * DIM + q * 4);
        uint2 r1 = *reinterpret_cast<const uint2*>(x + (size_t)n1.x * DIM + q * 4);
        uint2 r2 = *reinterpret_cast<const uint2*>(x + (size_t)n2.x * DIM + q * 4);
        uint2 r3 = *reinterpret_cast<const uint2*>(x + (size_t)n3.x * DIM + q * 4);
        float v0 = __int_as_float(n0.y), v1 = __int_as_float(n1.y);
        float v2 = __int_as_float(n2.y), v3 = __int_as_float(n3.y);
        s0 += v0 * bflo(r0.x); s1 += v0 * bfhi(r0.x); s2 += v0 * bflo(r0.y); s3 += v0 * bfhi(r0.y);
        s0 += v1 * bflo(r1.x); s1 += v1 * bfhi(r1.x); s2 += v1 * bflo(r1.y); s3 += v1 * bfhi(r1.y);
        s0 += v2 * bflo(r2.x); s1 += v2 * bfhi(r2.x); s2 += v2 * bflo(r2.y); s3 += v2 * bfhi(r2.y);
        s0 += v3 * bflo(r3.x); s1 += v3 * bfhi(r3.x); s2 += v3 * bflo(r3.y); s3 += v3 * bfhi(r3.y);
    }
    if (e < end) {                              // single predicated 16-wide tail step:
        int t0 = e + 4 * g;                     // group g takes contiguous run of 4
        int lim = end - 1;
        int c0 = min(t0, lim),     c1 = min(t0 + 1, lim);
        int c2 = min(t0 + 2, lim), c3 = min(t0 + 3, lim);
        int2 n0 = ent[c0];
        int2 n1 = ent[c1];
        int2 n2 = ent[c2];
        int2 n3 = ent[c3];
        uint2 r0 = *reinterpret_cast<const uint2*>(x + (size_t)n0.x * DIM + q * 4);
        uint2 r1 = *reinterpret_cast<const uint2*>(x + (size_t)n1.x * DIM + q * 4);
        uint2 r2 = *reinterpret_cast<const uint2*>(x + (size_t)n2.x * DIM + q * 4);
        uint2 r3 = *reinterpret_cast<const uint2*>(x + (size_t)n3.x * DIM + q * 4);
        float v0 = (t0     < end) ? __int_as_float(n0.y) : 0.f;
        float v1 = (t0 + 1 < end) ? __int_as_float(n1.y) : 0.f;
        float v2 = (t0 + 2 < end) ? __int_as_float(n2.y) : 0.f;
        float v3 = (t0 + 3 < end) ? __int_as_float(n3.y) : 0.f;
        s0 += v0 * bflo(r0.x); s1 += v0 * bfhi(r0.x); s2 += v0 * bflo(r0.y); s3 += v0 * bfhi(r0.y);
        s0 += v1 * bflo(r1.x); s1 += v1 * bfhi(r1.x); s2 += v1 * bflo(r1.y); s3 += v1 * bfhi(r1.y);
        s0 += v2 * bflo(r2.x); s1 += v2 * bfhi(r2.x); s2 += v2 * bflo(r2.y); s3 += v2 * bfhi(r2.y);
        s0 += v3 * bflo(r3.x); s1 += v3 * bfhi(r3.x); s2 += v3 * bflo(r3.y); s3 += v3 * bfhi(r3.y);
    }
    // combine the 4 edge-groups (butterfly over lane bits 4,5)
    s0 += __shfl_xor(s0, 16, 64); s0 += __shfl_xor(s0, 32, 64);
    s1 += __shfl_xor(s1, 16, 64); s1 += __shfl_xor(s1, 32, 64);
    s2 += __shfl_xor(s2, 16, 64); s2 += __shfl_xor(s2, 32, 64);
    s3 += __shfl_xor(s3, 16, 64); s3 += __shfl_xor(s3, 32, 64);
    if (g == 0) {                               // 16 lanes write the full row
        size_t base = (size_t)row * DIM + q * 4;
        if (op.out) {
            uint2 o;
            o.x = (unsigned)f2bf(s0) | ((unsigned)f2bf(s1) << 16);
            o.y = (unsigned)f2bf(s2) | ((unsigned)f2bf(s3) << 16);
            *reinterpret_cast<uint2*>(op.out + base) = o;
        }
        float4* a = reinterpret_cast<float4*>(op.acc + base);
        float4 av = *a;
        av.x += op.w * s0; av.y += op.w * s1; av.z += op.w * s2; av.w += op.w * s3;
        *a = av;
    }
}

// acc init + bf16 copies of inputs (after build; aliases build entries)
__global__ void init_acc(const float* __restrict__ ue, const float* __restrict__ ie,
                         float* __restrict__ accU, float* __restrict__ accI,
                         unsigned short* __restrict__ ueB, unsigned short* __restrict__ ieB,
                         int u4, int i4) {
    const float wu = 0.6f / 4.0f + 0.4f / 3.0f;
    const float wi = 0.25f;
    int i = blockIdx.x * blockDim.x + threadIdx.x;
    int st = gridDim.x * blockDim.x;
    int n4 = u4 + i4;
    for (; i < n4; i += st) {
        if (i < u4) {
            float4 v = reinterpret_cast<const float4*>(ue)[i];
            reinterpret_cast<float4*>(accU)[i] = make_float4(wu * v.x, wu * v.y, wu * v.z, wu * v.w);
            ushort4 b;
            b.x = f2bf(v.x); b.y = f2bf(v.y); b.z = f2bf(v.z); b.w = f2bf(v.w);
            reinterpret_cast<ushort4*>(ueB)[i] = b;
        } else {
            int j = i - u4;
            float4 v = reinterpret_cast<const float4*>(ie)[j];
            reinterpret_cast<float4*>(accI)[j] = make_float4(wi * v.x, wi * v.y, wi * v.z, wi * v.w);
            ushort4 b;
            b.x = f2bf(v.x); b.y = f2bf(v.y); b.z = f2bf(v.z); b.w = f2bf(v.w);
            reinterpret_cast<ushort4*>(ieB)[j] = b;
        }
    }
}

__global__ void finalize_kernel(float* __restrict__ out, int nrows) {
    int row = blockIdx.x * 4 + (threadIdx.x >> 6);
    if (row >= nrows) return;
    int d = threadIdx.x & 63;
    int idx = row * DIM + d;
    float val = out[idx];
    float sq = val * val;
    #pragma unroll
    for (int off = 32; off; off >>= 1) sq += __shfl_xor(sq, off, 64);
    out[idx] = val / fmaxf(sqrtf(sq), 1e-12f);
}

extern "C" void kernel_launch(void* const* d_in, const int* in_sizes, int n_in,
                              void* d_out, int out_size, void* d_ws, size_t ws_size,
                              hipStream_t stream) {
    const float* user_emb = (const float*)d_in[0];
    const float* item_emb = (const float*)d_in[1];
    const float* r_vals   = (const float*)d_in[2];
    const float* s_vals   = (const float*)d_in[3];
    const int*   r_rows   = (const int*)d_in[4];
    const int*   r_cols   = (const int*)d_in[5];
    const int*   s_rows   = (const int*)d_in[6];
    const int*   s_cols   = (const int*)d_in[7];

    const size_t U = (size_t)NUM_USERS * DIM;
    const size_t I = (size_t)NUM_ITEMS * DIM;

    // ---- workspace (~137 MB) ----
    int2* ent_sorted = (int2*)d_ws;                       // NNZ_TOT (67.2 MB), persistent
    char* region2 = (char*)(ent_sorted + NNZ_TOT);        // 67.2 MB union:
    int2* ent_bin = (int2*)region2;                       //   build-time entries
    unsigned short* ueB = (unsigned short*)region2;       //   spmm-time bf16 dense (57.6 MB)
    unsigned short* ieB = ueB + U;
    unsigned short* uA  = ieB + I;
    unsigned short* uB  = uA + U;
    unsigned short* iA  = uB + U;
    unsigned short* iB  = iA + I;
    int* cntPB   = (int*)(region2 + (size_t)NNZ_TOT * 8); // [NC][NBLK] (1.2 MB)
    int* bktBase = cntPB + NPB;                           // NC+1
    int* rPu = bktBase + NC + 1;                          // NUM_USERS+1
    int* rPi = rPu + NUM_USERS + 1;                       // NUM_ITEMS+1
    int* rPs = rPi + NUM_ITEMS + 1;                       // NUM_USERS+1

    float* accU = (float*)d_out;
    float* accI = (float*)d_out + U;

    dim3 blk(256);

    // ---- build: hist -> per-bucket scan -> top scan -> staged scatter -> sort ----
    hist_lds<<<NBLK, 1024, 0, stream>>>(r_rows, r_cols, s_rows, cntPB);
    scan_bkt<<<NC, NBLK, 0, stream>>>(cntPB, bktBase);
    scan_top<<<1, 1024, 0, stream>>>(bktBase);
    bin_pass<<<NBLK, 1024, 0, stream>>>(r_rows, r_cols, r_vals, s_rows, s_cols, s_vals,
                                        cntPB, bktBase, ent_bin);
    sort_buckets<<<NC, 512, 0, stream>>>(ent_bin, ent_sorted, bktBase, rPu, rPi, rPs);

    init_acc<<<2048, blk, 0, stream>>>(user_emb, item_emb, accU, accI, ueB, ieB,
                                       (int)(U / 4), (int)(I / 4));

    // ---- 3 bipartite layers, both directions fused per dispatch ----
    const float WU = 0.6f / 4.0f, WI = 0.25f, WS = 0.4f / 3.0f;
    int ub = (NUM_USERS + 3) / 4, ib = (NUM_ITEMS + 3) / 4;

    SpmmOp u1{rPu, ent_sorted, ieB, uA, accU, WU, NUM_USERS};
    SpmmOp i1{rPi, ent_sorted, ueB, iA, accI, WI, NUM_ITEMS};
    spmm2<<<ub + ib, blk, 0, stream>>>(u1, i1, ub);

    SpmmOp u2{rPu, ent_sorted, iA, uB, accU, WU, NUM_USERS};
    SpmmOp i2{rPi, ent_sorted, uA, iB, accI, WI, NUM_ITEMS};
    spmm2<<<ub + ib, blk, 0, stream>>>(u2, i2, ub);

    SpmmOp u3{rPu, ent_sorted, iB, nullptr, accU, WU, NUM_USERS};
    SpmmOp i3{rPi, ent_sorted, uB, nullptr, accI, WI, NUM_ITEMS};
    spmm2<<<ub + ib, blk, 0, stream>>>(u3, i3, ub);

    // ---- 2 social layers (uA dead after layer 2 -> reuse as social ping) ----
    SpmmOp so1{rPs, ent_sorted, ueB, uA, accU, WS, NUM_USERS};
    spmm2<<<ub, blk, 0, stream>>>(so1, so1, ub);
    SpmmOp so2{rPs, ent_sorted, uA, nullptr, accU, WS, NUM_USERS};
    spmm2<<<ub, blk, 0, stream>>>(so2, so2, ub);

    finalize_kernel<<<(NUM_USERS + NUM_ITEMS + 3) / 4, blk, 0, stream>>>(
        (float*)d_out, NUM_USERS + NUM_ITEMS);
}

// Round 16
// 635.440 us; speedup vs baseline: 1.7368x; 1.0126x over previous
//
#include <hip/hip_runtime.h>

constexpr int NUM_USERS = 100000;
constexpr int NUM_ITEMS = 50000;
constexpr int DIM = 64;
constexpr int NNZ_R = 3200000;
constexpr int NNZ_S = 2000000;
constexpr int NNZ_TOT = NNZ_R + NNZ_R + NNZ_S;   // 8.4M entries, one array

constexpr int BSH_U = 8, BROWS_U = 256;     // user/social buckets: 256 rows
constexpr int BSH_I = 7, BROWS_I = 128;     // item buckets: 128 rows
constexpr int NC_U = (NUM_USERS + BROWS_U - 1) / BROWS_U;   // 391
constexpr int NC_I = (NUM_ITEMS + BROWS_I - 1) / BROWS_I;   // 391
constexpr int NC_S = NC_U;                                  // 391
constexpr int NC = NC_U + NC_I + NC_S;                      // 1173
constexpr int NBLK = 256;                   // build blocks, 1/CU
constexpr int NPB = NBLK * NC;
constexpr int CHUNK_R = NNZ_R / NBLK;       // 12500 exact
constexpr int CHUNK_S = (NNZ_S + NBLK - 1) / NBLK;  // 7813

constexpr int SB_EDGES = 4096;              // R sub-batch: 4096 edges -> 8192 entries
constexpr int SB_PAIRS = 8192;

__device__ __forceinline__ float bf2f(unsigned short u) {
    return __uint_as_float((unsigned)u << 16);
}
__device__ __forceinline__ unsigned short f2bf(float f) {   // round-to-nearest-even
    unsigned u = __float_as_uint(f);
    return (unsigned short)((u + 0x7FFFu + ((u >> 16) & 1u)) >> 16);
}
__device__ __forceinline__ float bflo(unsigned r) { return __uint_as_float(r << 16); }
__device__ __forceinline__ float bfhi(unsigned r) { return __uint_as_float(r & 0xFFFF0000u); }

// ---- pass A: LDS histogram; per-(block,bucket) counts BUCKET-MAJOR ----
__global__ __launch_bounds__(1024) void hist_lds(const int* __restrict__ rr,
                                                 const int* __restrict__ rc,
                                                 const int* __restrict__ sr,
                                                 int* __restrict__ cntPB /* [NC][NBLK] */) {
    __shared__ int lds[NC];
    int k = blockIdx.x, tid = threadIdx.x;
    for (int c = tid; c < NC; c += 1024) lds[c] = 0;
    __syncthreads();
    int r0 = k * CHUNK_R, r1 = r0 + CHUNK_R;
    int s0 = k * CHUNK_S, s1 = min(s0 + CHUNK_S, NNZ_S);
    for (int i = r0 + tid; i < r1; i += 1024) {
        atomicAdd(&lds[rr[i] >> BSH_U], 1);
        atomicAdd(&lds[NC_U + (rc[i] >> BSH_I)], 1);
    }
    for (int i = s0 + tid; i < s1; i += 1024)
        atomicAdd(&lds[NC_U + NC_I + (sr[i] >> BSH_U)], 1);
    __syncthreads();
    for (int c = tid; c < NC; c += 1024) cntPB[c * NBLK + k] = lds[c];
}

// ---- per-bucket exscan over NBLK block-counts (one block per bucket) ----
__global__ __launch_bounds__(NBLK) void scan_bkt(int* __restrict__ cntPB,
                                                 int* __restrict__ bktTot) {
    int c = blockIdx.x, t = threadIdx.x;
    __shared__ int sh[NBLK];
    int v = cntPB[c * NBLK + t];
    sh[t] = v;
    __syncthreads();
    for (int off = 1; off < NBLK; off <<= 1) {
        int u = (t >= off) ? sh[t - off] : 0;
        __syncthreads();
        sh[t] += u;
        __syncthreads();
    }
    cntPB[c * NBLK + t] = sh[t] - v;
    if (t == NBLK - 1) bktTot[c] = sh[t];
}

// ---- tiny top-level exscan over NC bucket totals ----
__global__ __launch_bounds__(1024) void scan_top(int* __restrict__ B /* NC+1 */) {
    __shared__ int part[1024];
    int t = threadIdx.x;
    const int chunk = (NC + 1023) >> 10;
    int lo = t * chunk, hi = min(lo + chunk, NC);
    int s = 0;
    for (int i = lo; i < hi; ++i) s += B[i];
    part[t] = s;
    __syncthreads();
    for (int off = 1; off < 1024; off <<= 1) {
        int v = (t >= off) ? part[t - off] : 0;
        __syncthreads();
        part[t] += v;
        __syncthreads();
    }
    int excl = (t == 0) ? 0 : part[t - 1];
    for (int i = lo; i < hi; ++i) {
        int v = B[i];
        B[i] = excl;
        excl += v;
    }
    if (t == 1023) B[NC] = part[1023];
}

// ---- pass B: LDS-staged sub-batch sort, then wave-coalesced contiguous writes ----
__global__ __launch_bounds__(1024) void bin_pass(const int* __restrict__ rr,
                                                 const int* __restrict__ rc,
                                                 const float* __restrict__ rv,
                                                 const int* __restrict__ sr,
                                                 const int* __restrict__ sc,
                                                 const float* __restrict__ sv,
                                                 const int* __restrict__ cntPB,
                                                 const int* __restrict__ bktBase,
                                                 int2* __restrict__ ent) {
    __shared__ int cur[NC];
    __shared__ int cnt[NC];
    __shared__ int lstart[NC];
    __shared__ int lcur[NC];
    __shared__ int part[1024];
    __shared__ int2 stage[SB_PAIRS];
    __shared__ int gaddr[SB_PAIRS];
    int k = blockIdx.x, tid = threadIdx.x;
    for (int c = tid; c < NC; c += 1024)
        cur[c] = bktBase[c] + cntPB[c * NBLK + k];

    int r0 = k * CHUNK_R;
    for (int sb = 0; sb < CHUNK_R; sb += SB_EDGES) {
        int nE = min(SB_EDGES, CHUNK_R - sb);
        int base = r0 + sb;
        for (int c = tid; c < NC; c += 1024) { cnt[c] = 0; lcur[c] = 0; }
        __syncthreads();
        for (int i = tid; i < nE; i += 1024) {
            atomicAdd(&cnt[rr[base + i] >> BSH_U], 1);
            atomicAdd(&cnt[NC_U + (rc[base + i] >> BSH_I)], 1);
        }
        __syncthreads();
        int o0 = 2 * tid, o1 = 2 * tid + 1;
        int a = (o0 < NC) ? cnt[o0] : 0;
        int b = (o1 < NC) ? cnt[o1] : 0;
        part[tid] = a + b;
        __syncthreads();
        for (int off = 1; off < 1024; off <<= 1) {
            int v = (tid >= off) ? part[tid - off] : 0;
            __syncthreads();
            part[tid] += v;
            __syncthreads();
        }
        int ex = (tid == 0) ? 0 : part[tid - 1];
        if (o0 < NC) lstart[o0] = ex;
        if (o1 < NC) lstart[o1] = ex + a;
        __syncthreads();
        for (int i = tid; i < nE; i += 1024) {
            int r = rr[base + i], c = rc[base + i];
            int v = __float_as_int(rv[base + i]);
            int cu_ = r >> BSH_U;
            int j = atomicAdd(&lcur[cu_], 1);
            int lp = lstart[cu_] + j;
            stage[lp] = make_int2(((r & (BROWS_U - 1)) << 17) | c, v);
            gaddr[lp] = cur[cu_] + j;
            int ci_ = NC_U + (c >> BSH_I);
            int j2 = atomicAdd(&lcur[ci_], 1);
            int lp2 = lstart[ci_] + j2;
            stage[lp2] = make_int2(((c & (BROWS_I - 1)) << 17) | r, v);
            gaddr[lp2] = cur[ci_] + j2;
        }
        __syncthreads();
        int nP = 2 * nE;
        for (int s = tid; s < nP; s += 1024)
            ent[gaddr[s]] = stage[s];
        for (int c = tid; c < NC; c += 1024) cur[c] += cnt[c];
        __syncthreads();
    }

    int s0 = k * CHUNK_S, sEnd = min(s0 + CHUNK_S, NNZ_S);
    for (int sb = s0; sb < sEnd; sb += SB_PAIRS) {
        int nE = min(SB_PAIRS, sEnd - sb);
        for (int c = tid; c < NC; c += 1024) { cnt[c] = 0; lcur[c] = 0; }
        __syncthreads();
        for (int i = tid; i < nE; i += 1024)
            atomicAdd(&cnt[NC_U + NC_I + (sr[sb + i] >> BSH_U)], 1);
        __syncthreads();
        int o0 = 2 * tid, o1 = 2 * tid + 1;
        int a = (o0 < NC) ? cnt[o0] : 0;
        int b = (o1 < NC) ? cnt[o1] : 0;
        part[tid] = a + b;
        __syncthreads();
        for (int off = 1; off < 1024; off <<= 1) {
            int v = (tid >= off) ? part[tid - off] : 0;
            __syncthreads();
            part[tid] += v;
            __syncthreads();
        }
        int ex = (tid == 0) ? 0 : part[tid - 1];
        if (o0 < NC) lstart[o0] = ex;
        if (o1 < NC) lstart[o1] = ex + a;
        __syncthreads();
        for (int i = tid; i < nE; i += 1024) {
            int r = sr[sb + i];
            int cs_ = NC_U + NC_I + (r >> BSH_U);
            int j = atomicAdd(&lcur[cs_], 1);
            int lp = lstart[cs_] + j;
            stage[lp] = make_int2(((r & (BROWS_U - 1)) << 17) | sc[sb + i],
                                  __float_as_int(sv[sb + i]));
            gaddr[lp] = cur[cs_] + j;
        }
        __syncthreads();
        for (int s = tid; s < nE; s += 1024)
            ent[gaddr[s]] = stage[s];
        for (int c = tid; c < NC; c += 1024) cur[c] += cnt[c];
        __syncthreads();
    }
}

// ---- per-bucket counting sort (<=256 local rows) ----
__global__ __launch_bounds__(512) void sort_buckets(const int2* __restrict__ src,
                                                    int2* __restrict__ dst,
                                                    const int* __restrict__ bktBase,
                                                    int* __restrict__ rPu,
                                                    int* __restrict__ rPi,
                                                    int* __restrict__ rPs) {
    int gb = blockIdx.x;
    int* rowptr;
    int brows, lb, nrows;
    if (gb < NC_U)              { rowptr = rPu; brows = BROWS_U; lb = gb;               nrows = NUM_USERS; }
    else if (gb < NC_U + NC_I)  { rowptr = rPi; brows = BROWS_I; lb = gb - NC_U;        nrows = NUM_ITEMS; }
    else                        { rowptr = rPs; brows = BROWS_U; lb = gb - NC_U - NC_I; nrows = NUM_USERS; }
    int t = threadIdx.x;
    __shared__ int cnt[256];
    __shared__ int part[256];
    __shared__ int ofs[256];
    if (t < 256) cnt[t] = 0;
    __syncthreads();
    int b0 = bktBase[gb], b1 = bktBase[gb + 1];
    for (int i = b0 + t; i < b1; i += 512)
        atomicAdd(&cnt[(unsigned)src[i].x >> 17], 1);
    __syncthreads();
    if (t < 256) part[t] = cnt[t];
    __syncthreads();
    for (int off = 1; off < 256; off <<= 1) {
        int v = 0;
        if (t < 256 && t >= off) v = part[t - off];
        __syncthreads();
        if (t < 256) part[t] += v;
        __syncthreads();
    }
    if (t < 256) ofs[t] = part[t] - cnt[t];
    __syncthreads();
    int gr = lb * brows + t;
    if (t < brows && gr < nrows) rowptr[gr] = b0 + ofs[t];
    if (gb == 0 && t == 0) {
        rPu[NUM_USERS] = NNZ_R;
        rPi[NUM_ITEMS] = 2 * NNZ_R;
        rPs[NUM_USERS] = NNZ_TOT;
    }
    __syncthreads();
    for (int i = b0 + t; i < b1; i += 512) {
        int2 v = src[i];
        int lr = (unsigned)v.x >> 17;
        int pos = b0 + atomicAdd(&ofs[lr], 1);
        dst[pos] = make_int2(v.x & 0x1FFFF, v.y);
    }
}

// ---- CSR SpMM with acc-traffic elimination:
//      initsrc != null : acc = w0*bf16(initsrc) + w*sum   (no acc read)
//      initsrc == null, acc != null : acc += w*sum        (RMW)
//      acc == null : bf16 out only                        (deferred to finalize) ----
struct SpmmOp {
    const int* rowptr;
    const int2* ent;
    const unsigned short* x;        // bf16 rows [*][64]
    unsigned short* out;            // bf16, nullable
    float* acc;                     // f32 (d_out), nullable
    const unsigned short* initsrc;  // bf16 init term, nullable
    float w;
    float w0;
    int nrows;
};

__global__ __launch_bounds__(256, 4) void spmm2(SpmmOp A, SpmmOp B, int ablocks) {
    bool isA = (int)blockIdx.x < ablocks;
    SpmmOp op = isA ? A : B;
    int bid = isA ? blockIdx.x : blockIdx.x - ablocks;
    int row = bid * 4 + (threadIdx.x >> 6);
    if (row >= op.nrows) return;
    int lane = threadIdx.x & 63;
    int g = lane >> 4;          // edge group 0..3
    int q = lane & 15;          // quarter-row slot: dims 4q..4q+3
    const int2* __restrict__ ent = op.ent;
    const unsigned short* __restrict__ x = op.x;
    int e = op.rowptr[row], end = op.rowptr[row + 1];
    float s0 = 0.f, s1 = 0.f, s2 = 0.f, s3 = 0.f;
    for (; e + 16 <= end; e += 16) {            // 4 edges per group, 16 per wave-iter
        int2 n0 = ent[e + g];
        int2 n1 = ent[e + 4 + g];
        int2 n2 = ent[e + 8 + g];
        int2 n3 = ent[e + 12 + g];
        uint2 r0 = *reinterpret_cast<const uint2*>(x + (size_t)n0.x * DIM + q * 4);
        uint2 r1 = *reinterpret_cast<const uint2*>(x + (size_t)n1.x * DIM + q * 4);
        uint2 r2 = *reinterpret_cast<const uint2*>(x + (size_t)n2.x * DIM + q * 4);
        uint2 r3 = *reinterpret_cast<const uint2*>(x + (size_t)n3.x * DIM + q * 4);
        float v0 = __int_as_float(n0.y), v1 = __int_as_float(n1.y);
        float v2 = __int_as_float(n2.y), v3 = __int_as_float(n3.y);
        s0 += v0 * bflo(r0.x); s1 += v0 * bfhi(r0.x); s2 += v0 * bflo(r0.y); s3 += v0 * bfhi(r0.y);
        s0 += v1 * bflo(r1.x); s1 += v1 * bfhi(r1.x); s2 += v1 * bflo(r1.y); s3 += v1 * bfhi(r1.y);
        s0 += v2 * bflo(r2.x); s1 += v2 * bfhi(r2.x); s2 += v2 * bflo(r2.y); s3 += v2 * bfhi(r2.y);
        s0 += v3 * bflo(r3.x); s1 += v3 * bfhi(r3.x); s2 += v3 * bflo(r3.y); s3 += v3 * bfhi(r3.y);
    }
    if (e < end) {                              // single predicated 16-wide tail step
        int t0 = e + 4 * g;
        int lim = end - 1;
        int c0 = min(t0, lim),     c1 = min(t0 + 1, lim);
        int c2 = min(t0 + 2, lim), c3 = min(t0 + 3, lim);
        int2 n0 = ent[c0];
        int2 n1 = ent[c1];
        int2 n2 = ent[c2];
        int2 n3 = ent[c3];
        uint2 r0 = *reinterpret_cast<const uint2*>(x + (size_t)n0.x * DIM + q * 4);
        uint2 r1 = *reinterpret_cast<const uint2*>(x + (size_t)n1.x * DIM + q * 4);
        uint2 r2 = *reinterpret_cast<const uint2*>(x + (size_t)n2.x * DIM + q * 4);
        uint2 r3 = *reinterpret_cast<const uint2*>(x + (size_t)n3.x * DIM + q * 4);
        float v0 = (t0     < end) ? __int_as_float(n0.y) : 0.f;
        float v1 = (t0 + 1 < end) ? __int_as_float(n1.y) : 0.f;
        float v2 = (t0 + 2 < end) ? __int_as_float(n2.y) : 0.f;
        float v3 = (t0 + 3 < end) ? __int_as_float(n3.y) : 0.f;
        s0 += v0 * bflo(r0.x); s1 += v0 * bfhi(r0.x); s2 += v0 * bflo(r0.y); s3 += v0 * bfhi(r0.y);
        s0 += v1 * bflo(r1.x); s1 += v1 * bfhi(r1.x); s2 += v1 * bflo(r1.y); s3 += v1 * bfhi(r1.y);
        s0 += v2 * bflo(r2.x); s1 += v2 * bfhi(r2.x); s2 += v2 * bflo(r2.y); s3 += v2 * bfhi(r2.y);
        s0 += v3 * bflo(r3.x); s1 += v3 * bfhi(r3.x); s2 += v3 * bflo(r3.y); s3 += v3 * bfhi(r3.y);
    }
    s0 += __shfl_xor(s0, 16, 64); s0 += __shfl_xor(s0, 32, 64);
    s1 += __shfl_xor(s1, 16, 64); s1 += __shfl_xor(s1, 32, 64);
    s2 += __shfl_xor(s2, 16, 64); s2 += __shfl_xor(s2, 32, 64);
    s3 += __shfl_xor(s3, 16, 64); s3 += __shfl_xor(s3, 32, 64);
    if (g == 0) {                               // 16 lanes write the full row
        size_t base = (size_t)row * DIM + q * 4;
        if (op.out) {
            uint2 o;
            o.x = (unsigned)f2bf(s0) | ((unsigned)f2bf(s1) << 16);
            o.y = (unsigned)f2bf(s2) | ((unsigned)f2bf(s3) << 16);
            *reinterpret_cast<uint2*>(op.out + base) = o;
        }
        if (op.acc) {
            float4* a = reinterpret_cast<float4*>(op.acc + base);
            float4 av;
            if (op.initsrc) {
                uint2 iv = *reinterpret_cast<const uint2*>(op.initsrc + base);
                av.x = op.w0 * bflo(iv.x); av.y = op.w0 * bfhi(iv.x);
                av.z = op.w0 * bflo(iv.y); av.w = op.w0 * bfhi(iv.y);
            } else {
                av = *a;
            }
            av.x += op.w * s0; av.y += op.w * s1; av.z += op.w * s2; av.w += op.w * s3;
            *a = av;
        }
    }
}

// bf16 copies of the input embeddings (runs after build; aliases ent_bin region)
__global__ void to_bf16(const float* __restrict__ ue, const float* __restrict__ ie,
                        unsigned short* __restrict__ ueB, unsigned short* __restrict__ ieB,
                        int u4, int i4) {
    int i = blockIdx.x * blockDim.x + threadIdx.x;
    int st = gridDim.x * blockDim.x;
    int n4 = u4 + i4;
    for (; i < n4; i += st) {
        if (i < u4) {
            float4 v = reinterpret_cast<const float4*>(ue)[i];
            ushort4 b;
            b.x = f2bf(v.x); b.y = f2bf(v.y); b.z = f2bf(v.z); b.w = f2bf(v.w);
            reinterpret_cast<ushort4*>(ueB)[i] = b;
        } else {
            int j = i - u4;
            float4 v = reinterpret_cast<const float4*>(ie)[j];
            ushort4 b;
            b.x = f2bf(v.x); b.y = f2bf(v.y); b.z = f2bf(v.z); b.w = f2bf(v.w);
            reinterpret_cast<ushort4*>(ieB)[j] = b;
        }
    }
}

// finalize: fold deferred last-layer terms, then L2-normalize per row
__global__ void finalize_kernel(float* __restrict__ out,
                                const unsigned short* __restrict__ uC,  // u3
                                const unsigned short* __restrict__ s2,  // social layer 2
                                const unsigned short* __restrict__ iC) { // i3
    const float WU = 0.6f / 4.0f, WS = 0.4f / 3.0f, WI = 0.25f;
    int row = blockIdx.x * 4 + (threadIdx.x >> 6);
    if (row >= NUM_USERS + NUM_ITEMS) return;
    int d = threadIdx.x & 63;
    size_t idx = (size_t)row * DIM + d;
    float val = out[idx];
    if (row < NUM_USERS) {
        val += WU * bf2f(uC[idx]) + WS * bf2f(s2[idx]);
    } else {
        size_t iidx = idx - (size_t)NUM_USERS * DIM;
        val += WI * bf2f(iC[iidx]);
    }
    float sq = val * val;
    #pragma unroll
    for (int off = 32; off; off >>= 1) sq += __shfl_xor(sq, off, 64);
    out[idx] = val / fmaxf(sqrtf(sq), 1e-12f);
}

extern "C" void kernel_launch(void* const* d_in, const int* in_sizes, int n_in,
                              void* d_out, int out_size, void* d_ws, size_t ws_size,
                              hipStream_t stream) {
    const float* user_emb = (const float*)d_in[0];
    const float* item_emb = (const float*)d_in[1];
    const float* r_vals   = (const float*)d_in[2];
    const float* s_vals   = (const float*)d_in[3];
    const int*   r_rows   = (const int*)d_in[4];
    const int*   r_cols   = (const int*)d_in[5];
    const int*   s_rows   = (const int*)d_in[6];
    const int*   s_cols   = (const int*)d_in[7];

    const size_t U = (size_t)NUM_USERS * DIM;
    const size_t I = (size_t)NUM_ITEMS * DIM;

    // ---- workspace (~140 MB) ----
    int2* ent_sorted = (int2*)d_ws;                       // NNZ_TOT (67.2 MB), persistent
    char* region2 = (char*)(ent_sorted + NNZ_TOT);        // 70.4 MB union:
    int2* ent_bin = (int2*)region2;                       //   build-time entries (67.2)
    unsigned short* ueB = (unsigned short*)region2;       //   bf16: [ueB U][ieB I][uA U]
    unsigned short* ieB = ueB + U;                        //         [uB U][iA I][iB I][uC U]
    unsigned short* uA  = ieB + I;                        //   = (4U+3I)*2 = 70.4 MB
    unsigned short* uB  = uA + U;
    unsigned short* iA  = uB + U;
    unsigned short* iB  = iA + I;
    unsigned short* uC  = iB + I;
    unsigned short* s1b = uA;    // social 1 out: uA dead after D2
    unsigned short* s2b = ueB;   // social 2 out: ueB dead after so1
    unsigned short* iCb = ieB;   // i3 out: ieB dead after D1
    int* cntPB   = (int*)(uC + U);                        // [NC][NBLK] (1.2 MB)
    int* bktBase = cntPB + NPB;                           // NC+1
    int* rPu = bktBase + NC + 1;                          // NUM_USERS+1
    int* rPi = rPu + NUM_USERS + 1;                       // NUM_ITEMS+1
    int* rPs = rPi + NUM_ITEMS + 1;                       // NUM_USERS+1

    float* accU = (float*)d_out;
    float* accI = (float*)d_out + U;

    dim3 blk(256);

    // ---- build: hist -> per-bucket scan -> top scan -> staged scatter -> sort ----
    hist_lds<<<NBLK, 1024, 0, stream>>>(r_rows, r_cols, s_rows, cntPB);
    scan_bkt<<<NC, NBLK, 0, stream>>>(cntPB, bktBase);
    scan_top<<<1, 1024, 0, stream>>>(bktBase);
    bin_pass<<<NBLK, 1024, 0, stream>>>(r_rows, r_cols, r_vals, s_rows, s_cols, s_vals,
                                        cntPB, bktBase, ent_bin);
    sort_buckets<<<NC, 512, 0, stream>>>(ent_bin, ent_sorted, bktBase, rPu, rPi, rPs);

    to_bf16<<<2048, blk, 0, stream>>>(user_emb, item_emb, ueB, ieB,
                                      (int)(U / 4), (int)(I / 4));

    const float WU = 0.6f / 4.0f, WI = 0.25f, WS = 0.4f / 3.0f;
    const float WU0 = WU + WS;   // e_u weight: 0.15 + 0.4/3
    int ub = (NUM_USERS + 3) / 4, ib = (NUM_ITEMS + 3) / 4;

    // D1: acc-init (no acc read): accU = WU0*e_u + WU*u1 ; accI = WI*e_i + WI*i1
    SpmmOp u1{rPu, ent_sorted, ieB, uA, accU, ueB, WU, WU0, NUM_USERS};
    SpmmOp i1{rPi, ent_sorted, ueB, iA, accI, ieB, WI, WI, NUM_ITEMS};
    spmm2<<<ub + ib, blk, 0, stream>>>(u1, i1, ub);

    // D2: RMW
    SpmmOp u2{rPu, ent_sorted, iA, uB, accU, nullptr, WU, 0.f, NUM_USERS};
    SpmmOp i2{rPi, ent_sorted, uA, iB, accI, nullptr, WI, 0.f, NUM_ITEMS};
    spmm2<<<ub + ib, blk, 0, stream>>>(u2, i2, ub);

    // so1: RMW accU += WS*s1, out s1 (into uA, dead after D2)
    SpmmOp so1{rPs, ent_sorted, ueB, s1b, accU, nullptr, WS, 0.f, NUM_USERS};
    spmm2<<<ub, blk, 0, stream>>>(so1, so1, ub);

    // so2: out-only s2 (into ueB, dead after so1); folded in finalize
    SpmmOp so2{rPs, ent_sorted, s1b, s2b, nullptr, nullptr, 0.f, 0.f, NUM_USERS};
    spmm2<<<ub, blk, 0, stream>>>(so2, so2, ub);

    // D3: out-only u3 -> uC, i3 -> ieB(iC); folded in finalize
    SpmmOp u3{rPu, ent_sorted, iB, uC, nullptr, nullptr, 0.f, 0.f, NUM_USERS};
    SpmmOp i3{rPi, ent_sorted, uB, iCb, nullptr, nullptr, 0.f, 0.f, NUM_ITEMS};
    spmm2<<<ub + ib, blk, 0, stream>>>(u3, i3, ub);

    finalize_kernel<<<(NUM_USERS + NUM_ITEMS + 3) / 4, blk, 0, stream>>>(
        (float*)d_out, uC, s2b, iCb);
}